// Round 16
// baseline (536.053 us; speedup 1.0000x reference)
//
#include <hip/hip_runtime.h>
#include <hip/hip_bf16.h>

#define SEQ 49
#define CH 768
#define NH 24
#define HD 32
#define NB 1024
#define NWIN 64
#define MTOT (NB*SEQ)      // 50176

typedef __hip_bfloat16 bf16;
typedef __attribute__((ext_vector_type(8))) short short8;
typedef __attribute__((ext_vector_type(4))) short short4v;
typedef __attribute__((ext_vector_type(4))) float f32x4;

#define MD  ((size_t)MTOT * HD)     // elems per head plane: 1,605,632
#define NHMD ((size_t)NH * MD)      // elems per q/k/v section

__device__ __forceinline__ void gload16(const void* g, void* l) {
  __builtin_amdgcn_global_load_lds((__attribute__((address_space(1))) void*)g,
                                   (__attribute__((address_space(3))) void*)l,
                                   16, 0, 0);
}

__device__ __forceinline__ float bf2f(short s) {
  return __uint_as_float(((unsigned int)(unsigned short)s) << 16);
}

// ---------------- converters ----------------
__global__ void cvt_bf16(const float* __restrict__ in, bf16* __restrict__ o, int n4) {
  int i = blockIdx.x * blockDim.x + threadIdx.x;
  if (i >= n4) return;
  float4 v = ((const float4*)in)[i];
  union { bf16 b[4]; short4 s; } u;
  u.b[0] = __float2bfloat16(v.x);
  u.b[1] = __float2bfloat16(v.y);
  u.b[2] = __float2bfloat16(v.z);
  u.b[3] = __float2bfloat16(v.w);
  ((short4*)o)[i] = u.s;
}

// comb_p[s*24+h][jj][lane][8] (bf16), fragment-ordered, PRE-SCALED by log2(e);
// pads hold -1e30 (exp2 -> 0)
__global__ void build_comb(const float* __restrict__ table, const int* __restrict__ rpi,
                           const float* __restrict__ smask, bf16* __restrict__ comb) {
  int i = blockIdx.x * blockDim.x + threadIdx.x;
  if (i >= NWIN * NH * 1024) return;
  int idx = i * 4;
  int e0 = idx & 7;
  int l = (idx >> 3) & 63;
  int jj = (idx >> 9) & 7;
  int sh = idx >> 12;
  int h = sh % NH;
  int s = sh / NH;
  union { bf16 b[4]; short4 v; } u;
#pragma unroll
  for (int k = 0; k < 4; k++) {
    int j = jj * 8 + e0 + k;
    int mt = j >> 4, nt = (j >> 2) & 3, r = j & 3;
    int m = 16 * mt + 4 * (l >> 4) + r;
    int n = 16 * nt + (l & 15);
    float v = -1e30f;
    if (m < SEQ && n < SEQ)
      v = (table[rpi[m * SEQ + n] * NH + h] + smask[s * SEQ * SEQ + m * SEQ + n])
          * 1.4426950408889634f;
    u.b[k] = __float2bfloat16(v);
  }
  *(short4*)(comb + idx) = u.v;
}

// ---------------- kernel 1: QKV GEMM, 256x256 tile, BK=64 ----------------
// 4 phases/K-tile, counted vmcnt (T4): issue order B0B1|B2B3|A0A2|A1A3,
// entry waits p0:vmcnt(2), p2:vmcnt(4) (last tile: 0). Loads span barriers.
__global__ __launch_bounds__(512) void qkv_gemm(
    const bf16* __restrict__ A, const bf16* __restrict__ Bw,
    const float* __restrict__ bias, bf16* __restrict__ C)
{
  extern __shared__ __align__(16) bf16 lds[];  // [A0|A1|B0|B1] x 16384 elems
  const int tid = threadIdx.x;
  const int w = tid >> 6, l = tid & 63;
  const int lr = l & 15, lg = l >> 4;
  const int wm = w >> 2, wn = w & 3;

  const int flat = blockIdx.x;
  const int xcd = flat & 7, lid = flat >> 3;
  const int wgid = (xcd < 4 ? xcd * 221 : 884 + (xcd - 4) * 220) + lid;
  const int bm = wgid / 9, bn = wgid - 9 * bm;

  const bf16* gA[4];
  const bf16* gB[4];
  int ldst[4];
#pragma unroll
  for (int j = 0; j < 4; j++) {
    int c = j * 512 + tid;
    int row = c >> 3, cpos = c & 7;
    int srcch = cpos ^ (row & 7);
    gA[j] = A + ((size_t)(bm * 256 + row)) * CH + srcch * 8;
    gB[j] = Bw + ((size_t)(bn * 256 + row)) * CH + srcch * 8;
    ldst[j] = c * 8;
  }

  f32x4 acc[8][4];
  f32x4 zero4 = {0.f, 0.f, 0.f, 0.f};
#pragma unroll
  for (int i = 0; i < 8; i++)
#pragma unroll
    for (int j = 0; j < 4; j++) acc[i][j] = zero4;

  int offA[8][2], offB[4][2];
#pragma unroll
  for (int mi = 0; mi < 8; mi++)
#pragma unroll
    for (int ks = 0; ks < 2; ks++) {
      int rowa = wm * 128 + mi * 16 + lr;
      offA[mi][ks] = rowa * 64 + ((lg + 4 * ks) ^ (rowa & 7)) * 8;
    }
#pragma unroll
  for (int nj = 0; nj < 4; nj++)
#pragma unroll
    for (int ks = 0; ks < 2; ks++) {
      int rowb = wn * 64 + nj * 16 + lr;
      offB[nj][ks] = rowb * 64 + ((lg + 4 * ks) ^ (rowb & 7)) * 8;
    }

  // prologue: tile 0 -> buf0, issue order B0,B1,B2,B3,A0,A2,A1,A3
  gload16(gB[0], lds + 32768 + ldst[0]);
  gload16(gB[1], lds + 32768 + ldst[1]);
  gload16(gB[2], lds + 32768 + ldst[2]);
  gload16(gB[3], lds + 32768 + ldst[3]);
  gload16(gA[0], lds + ldst[0]);
  gload16(gA[2], lds + ldst[2]);
  gload16(gA[1], lds + ldst[1]);
  gload16(gA[3], lds + ldst[3]);

  for (int t = 0; t < 12; ++t) {
    const int cur = t & 1;
    const bf16* cA = lds + cur * 16384;
    const bf16* cB = lds + 32768 + cur * 16384;
    bf16* nA = lds + (cur ^ 1) * 16384;
    bf16* nB = lds + 32768 + (cur ^ 1) * 16384;
    const int kk = (t + 1) * 64;
    const bool pf = (t < 11);
#pragma unroll
    for (int p = 0; p < 4; ++p) {
      const int hp = p >> 1, ks = p & 1;
      if (p == 0) {
        asm volatile("s_waitcnt vmcnt(2)" ::: "memory");   // A0,A2,B* of tile t landed
      } else if (p == 2) {
        if (pf) asm volatile("s_waitcnt vmcnt(4)" ::: "memory");  // A1,A3 of tile t landed
        else    asm volatile("s_waitcnt vmcnt(0)" ::: "memory");
      }
      __builtin_amdgcn_sched_barrier(0);
      __builtin_amdgcn_s_barrier();          // propagate per-wave completion CU-wide
      __builtin_amdgcn_sched_barrier(0);
      short8 af[4], bfv[4];
#pragma unroll
      for (int mi = 0; mi < 4; mi++) af[mi] = *(const short8*)(cA + offA[hp * 4 + mi][ks]);
#pragma unroll
      for (int nj = 0; nj < 4; nj++) bfv[nj] = *(const short8*)(cB + offB[nj][ks]);
      if (pf) {
        if (p == 0) { gload16(gB[0] + kk, nB + ldst[0]); gload16(gB[1] + kk, nB + ldst[1]); }
        if (p == 1) { gload16(gB[2] + kk, nB + ldst[2]); gload16(gB[3] + kk, nB + ldst[3]); }
        if (p == 2) { gload16(gA[0] + kk, nA + ldst[0]); gload16(gA[2] + kk, nA + ldst[2]); }
        if (p == 3) { gload16(gA[1] + kk, nA + ldst[1]); gload16(gA[3] + kk, nA + ldst[3]); }
      }
      asm volatile("s_waitcnt lgkmcnt(0)" ::: "memory");
      __builtin_amdgcn_sched_barrier(0);
      __builtin_amdgcn_s_setprio(1);
#pragma unroll
      for (int mi = 0; mi < 4; mi++)
#pragma unroll
        for (int nj = 0; nj < 4; nj++)
          acc[hp * 4 + mi][nj] =
              __builtin_amdgcn_mfma_f32_16x16x32_bf16(af[mi], bfv[nj], acc[hp * 4 + mi][nj], 0, 0, 0);
      __builtin_amdgcn_s_setprio(0);
    }
  }

  const float scale = 0.25503487724583985f;  // log2(e)/sqrt(32)
  const int colbase = bn * 256 + 64 * wn;
  const int rowbase = bm * 256 + 128 * wm;
#pragma unroll
  for (int nj = 0; nj < 4; nj++) {
    const int cb16 = colbase + 16 * nj;
    const int sec = cb16 / 768;              // 0=q 1=k 2=v
    const int rem = cb16 - sec * 768;
    const int h = rem >> 5;
    const int dbase = rem & 31;              // 0 or 16
    float bv = bias[cb16 + lr];
    if (sec == 2) {
      const size_t vbase = 2 * NHMD + ((size_t)h * HD + dbase + lr) * MTOT;
#pragma unroll
      for (int mi = 0; mi < 8; mi++) {
        size_t row = rowbase + 16 * mi + 4 * lg;
        union { bf16 b[4]; short4 s; } u;
#pragma unroll
        for (int r = 0; r < 4; r++) u.b[r] = __float2bfloat16(acc[mi][nj][r] + bv);
        *(short4*)(C + vbase + row) = u.s;
      }
    } else {
      const float mul = (sec == 0) ? scale : 1.0f;
      const size_t base = (size_t)sec * NHMD + (size_t)h * MD + dbase + lr;
#pragma unroll
      for (int mi = 0; mi < 8; mi++) {
#pragma unroll
        for (int r = 0; r < 4; r++) {
          size_t row = rowbase + 16 * mi + 4 * lg + r;
          C[base + row * HD] = __float2bfloat16((acc[mi][nj][r] + bv) * mul);
        }
      }
    }
  }
}

// ---------------- kernel 2: attention (r14 exact: per-mt phased, 4 waves/SIMD) ----------------
__global__ __launch_bounds__(256, 4) void attn_kernel(
    const bf16* __restrict__ qkvT, const bf16* __restrict__ comb,
    bf16* __restrict__ aout)
{
  __shared__ __align__(16) bf16 P[4][64 * 72];
  const int tid = threadIdx.x;
  const int w = tid >> 6, l = tid & 63;
  const int lr = l & 15, lg = l >> 4;
  const int b = blockIdx.x;
  const int h = blockIdx.y * 4 + w;
  const size_t rowb = (size_t)b * SEQ;
  f32x4 zero4 = {0.f, 0.f, 0.f, 0.f};

  const bf16* qb = qkvT + (size_t)h * MD + rowb * HD;          // q pre-scaled (log2e/sqrt32)
  const bf16* kb = qkvT + NHMD + (size_t)h * MD + rowb * HD;
  const bf16* vT = qkvT + 2 * NHMD + (size_t)h * HD * MTOT;    // [32][M]

  short8 kf[4];
#pragma unroll
  for (int nt = 0; nt < 4; nt++)
    kf[nt] = *(const short8*)(kb + (16 * nt + lr) * HD + 8 * lg);

  short8 pb[2][2];
#pragma unroll
  for (int kt = 0; kt < 2; kt++)
#pragma unroll
    for (int dt = 0; dt < 2; dt++)
      pb[kt][dt] = *(const short8*)(vT + ((size_t)(16 * dt + lr)) * MTOT + rowb + 32 * kt + 8 * lg);

  const bf16* cbp = comb + (((size_t)(b & (NWIN - 1)) * NH + h) << 12);
  float inv[4][4];

#pragma unroll
  for (int mt = 0; mt < 4; mt++) {
    short8 qf = *(const short8*)(qb + (16 * mt + lr) * HD + 8 * lg);
    f32x4 s4[4];
#pragma unroll
    for (int nt = 0; nt < 4; nt++)
      s4[nt] = __builtin_amdgcn_mfma_f32_16x16x32_bf16(qf, kf[nt], zero4, 0, 0, 0);
    short8 c0 = *(const short8*)(cbp + ((2 * mt) * 64 + l) * 8);
    short8 c1 = *(const short8*)(cbp + ((2 * mt + 1) * 64 + l) * 8);
#pragma unroll
    for (int e = 0; e < 8; e++) s4[e >> 2][e & 3] += bf2f(c0[e]);
#pragma unroll
    for (int e = 0; e < 8; e++) s4[2 + (e >> 2)][e & 3] += bf2f(c1[e]);
#pragma unroll
    for (int r = 0; r < 4; r++) {
      float t = 0.f;
#pragma unroll
      for (int nt = 0; nt < 4; nt++) {
        float e = exp2f(s4[nt][r]);
        s4[nt][r] = e;
        t += e;
      }
      t += __shfl_xor(t, 1, 64);
      t += __shfl_xor(t, 2, 64);
      t += __shfl_xor(t, 4, 64);
      t += __shfl_xor(t, 8, 64);
      inv[mt][r] = 1.0f / t;
    }
#pragma unroll
    for (int nt = 0; nt < 4; nt++)
#pragma unroll
      for (int r = 0; r < 4; r++)
        P[w][(16 * mt + 4 * lg + r) * 72 + 16 * nt + lr] = __float2bfloat16(s4[nt][r]);
  }

  f32x4 o[4][2];
#pragma unroll
  for (int mt = 0; mt < 4; mt++) { o[mt][0] = zero4; o[mt][1] = zero4; }
#pragma unroll
  for (int kt = 0; kt < 2; kt++) {
    short8 pa[4];
#pragma unroll
    for (int mt = 0; mt < 4; mt++)
      pa[mt] = *(const short8*)(&P[w][(16 * mt + lr) * 72 + 32 * kt + 8 * lg]);
#pragma unroll
    for (int mt = 0; mt < 4; mt++)
#pragma unroll
      for (int dt = 0; dt < 2; dt++)
        o[mt][dt] = __builtin_amdgcn_mfma_f32_16x16x32_bf16(pa[mt], pb[kt][dt], o[mt][dt], 0, 0, 0);
  }

#pragma unroll
  for (int mt = 0; mt < 4; mt++)
#pragma unroll
    for (int dt = 0; dt < 2; dt++)
#pragma unroll
      for (int r = 0; r < 4; r++) {
        int m = 16 * mt + 4 * lg + r;
        if (m < SEQ)
          aout[(rowb + m) * CH + h * HD + 16 * dt + lr] =
              __float2bfloat16(o[mt][dt][r] * inv[mt][r]);
      }
}

// ---------------- kernel 3: proj GEMM, 4-phase counted vmcnt (qkv schedule) ----------------
// issue order B0,B1|B2,B3|A0,A2|A1,A3; entry waits p0:vmcnt(2), p2:vmcnt(4).
__global__ __launch_bounds__(256) void proj_gemm(
    const bf16* __restrict__ A, const bf16* __restrict__ Bw,
    const float* __restrict__ bias, const bf16* __restrict__ xb,
    bf16* __restrict__ Y)
{
  __shared__ __align__(16) bf16 As[2 * 128 * 64];
  __shared__ __align__(16) bf16 Bs[2 * 128 * 64];
  const int tid = threadIdx.x;
  const int w = tid >> 6, l = tid & 63;
  const int lr = l & 15, lg = l >> 4;
  const int wm = w >> 1, wn = w & 1;

  const int flat = blockIdx.x;                 // 2352 = 8 x 294
  const int wg = (flat & 7) * 294 + (flat >> 3);
  const int bm = wg / 6, bn = wg - 6 * (wg / 6);

  const bf16* gA[4];
  const bf16* gB[4];
  int ldst[4];
#pragma unroll
  for (int j = 0; j < 4; j++) {
    int c = j * 256 + tid;
    int row = c >> 3, cpos = c & 7;
    int srcch = cpos ^ (row & 7);
    gA[j] = A + ((size_t)(bm * 128 + row)) * CH + srcch * 8;
    gB[j] = Bw + ((size_t)(bn * 128 + row)) * CH + srcch * 8;
    ldst[j] = c * 8;
  }

  f32x4 acc[4][4];
  f32x4 zero4 = {0.f, 0.f, 0.f, 0.f};
#pragma unroll
  for (int i = 0; i < 4; i++)
#pragma unroll
    for (int j = 0; j < 4; j++) acc[i][j] = zero4;

  int offA[4][2], offB[4][2];
#pragma unroll
  for (int mi = 0; mi < 4; mi++) {
#pragma unroll
    for (int ks = 0; ks < 2; ks++) {
      int rowa = 64 * wm + 16 * mi + lr;
      offA[mi][ks] = rowa * 64 + ((lg + 4 * ks) ^ (rowa & 7)) * 8;
      int rowb = 64 * wn + 16 * mi + lr;
      offB[mi][ks] = rowb * 64 + ((lg + 4 * ks) ^ (rowb & 7)) * 8;
    }
  }

  // prologue: tile 0, issue order B0,B1,B2,B3,A0,A2,A1,A3
  gload16(gB[0], Bs + ldst[0]);
  gload16(gB[1], Bs + ldst[1]);
  gload16(gB[2], Bs + ldst[2]);
  gload16(gB[3], Bs + ldst[3]);
  gload16(gA[0], As + ldst[0]);
  gload16(gA[2], As + ldst[2]);
  gload16(gA[1], As + ldst[1]);
  gload16(gA[3], As + ldst[3]);

  for (int t = 0; t < 12; ++t) {
    const int base = (t & 1) * 8192;
    const bf16* cA = As + base;
    const bf16* cB = Bs + base;
    bf16* nA = As + (base ^ 8192);
    bf16* nB = Bs + (base ^ 8192);
    const int kk = (t + 1) * 64;
    const bool pf = (t < 11);
#pragma unroll
    for (int p = 0; p < 4; ++p) {
      const int hp = p >> 1, ks = p & 1;
      if (p == 0) {
        asm volatile("s_waitcnt vmcnt(2)" ::: "memory");
      } else if (p == 2) {
        if (pf) asm volatile("s_waitcnt vmcnt(4)" ::: "memory");
        else    asm volatile("s_waitcnt vmcnt(0)" ::: "memory");
      }
      __builtin_amdgcn_sched_barrier(0);
      __builtin_amdgcn_s_barrier();
      __builtin_amdgcn_sched_barrier(0);
      short8 af[2], bfv[4];
#pragma unroll
      for (int i = 0; i < 2; i++) af[i] = *(const short8*)(cA + offA[hp * 2 + i][ks]);
#pragma unroll
      for (int nj = 0; nj < 4; nj++) bfv[nj] = *(const short8*)(cB + offB[nj][ks]);
      if (pf) {
        if (p == 0) { gload16(gB[0] + kk, nB + ldst[0]); gload16(gB[1] + kk, nB + ldst[1]); }
        if (p == 1) { gload16(gB[2] + kk, nB + ldst[2]); gload16(gB[3] + kk, nB + ldst[3]); }
        if (p == 2) { gload16(gA[0] + kk, nA + ldst[0]); gload16(gA[2] + kk, nA + ldst[2]); }
        if (p == 3) { gload16(gA[1] + kk, nA + ldst[1]); gload16(gA[3] + kk, nA + ldst[3]); }
      }
      asm volatile("s_waitcnt lgkmcnt(0)" ::: "memory");
      __builtin_amdgcn_sched_barrier(0);
      __builtin_amdgcn_s_setprio(1);
#pragma unroll
      for (int i = 0; i < 2; i++)
#pragma unroll
        for (int nj = 0; nj < 4; nj++)
          acc[hp * 2 + i][nj] =
              __builtin_amdgcn_mfma_f32_16x16x32_bf16(af[i], bfv[nj], acc[hp * 2 + i][nj], 0, 0, 0);
      __builtin_amdgcn_s_setprio(0);
    }
  }

  const int colbase = bn * 128 + 64 * wn;
  const int rowbase = bm * 128 + 64 * wm;
#pragma unroll
  for (int nj = 0; nj < 4; nj++) {
    int col = colbase + 16 * nj + lr;
    float bv = bias[col];
#pragma unroll
    for (int mi = 0; mi < 4; mi++) {
#pragma unroll
      for (int r = 0; r < 4; r++) {
        size_t row = rowbase + 16 * mi + 4 * lg + r;
        float v = acc[mi][nj][r] + bv + bf2f(((const short*)xb)[row * CH + col]);
        Y[row * CH + col] = __float2bfloat16(v);
      }
    }
  }
}

// ---------------- kernel 4: LayerNorm ----------------
__global__ __launch_bounds__(256) void ln_kernel(
    const bf16* __restrict__ Y, const float* __restrict__ g,
    const float* __restrict__ be, float* __restrict__ out)
{
  const int w = threadIdx.x >> 6, l = threadIdx.x & 63;
  const size_t r = (size_t)blockIdx.x * 4 + w;
  const bf16* yr = Y + r * CH;

  short8 a = *(const short8*)(yr + 8 * l);
  short4v b4 = *(const short4v*)(yr + 512 + 4 * l);
  float v[12];
#pragma unroll
  for (int j = 0; j < 8; j++) v[j] = bf2f(a[j]);
#pragma unroll
  for (int j = 0; j < 4; j++) v[8 + j] = bf2f(b4[j]);

  float s1 = 0.f, s2 = 0.f;
#pragma unroll
  for (int j = 0; j < 12; j++) { s1 += v[j]; s2 += v[j] * v[j]; }
#pragma unroll
  for (int m = 1; m <= 32; m <<= 1) {
    s1 += __shfl_xor(s1, m, 64);
    s2 += __shfl_xor(s2, m, 64);
  }
  float mu = s1 * (1.0f / 768.0f);
  float var = s2 * (1.0f / 768.0f) - mu * mu;
  float rs = rsqrtf(var + 1e-5f);

  float4 g0 = *(const float4*)(g + 8 * l);
  float4 g1 = *(const float4*)(g + 8 * l + 4);
  float4 g2 = *(const float4*)(g + 512 + 4 * l);
  float4 b0 = *(const float4*)(be + 8 * l);
  float4 b1 = *(const float4*)(be + 8 * l + 4);
  float4 b2 = *(const float4*)(be + 512 + 4 * l);

  float4 o0, o1, o2;
  o0.x = (v[0] - mu) * rs * g0.x + b0.x;
  o0.y = (v[1] - mu) * rs * g0.y + b0.y;
  o0.z = (v[2] - mu) * rs * g0.z + b0.z;
  o0.w = (v[3] - mu) * rs * g0.w + b0.w;
  o1.x = (v[4] - mu) * rs * g1.x + b1.x;
  o1.y = (v[5] - mu) * rs * g1.y + b1.y;
  o1.z = (v[6] - mu) * rs * g1.z + b1.z;
  o1.w = (v[7] - mu) * rs * g1.w + b1.w;
  o2.x = (v[8] - mu) * rs * g2.x + b2.x;
  o2.y = (v[9] - mu) * rs * g2.y + b2.y;
  o2.z = (v[10] - mu) * rs * g2.z + b2.z;
  o2.w = (v[11] - mu) * rs * g2.w + b2.w;

  float* orow = out + r * CH;
  *(float4*)(orow + 8 * l) = o0;
  *(float4*)(orow + 8 * l + 4) = o1;
  *(float4*)(orow + 512 + 4 * l) = o2;
}

// ---------------- launch ----------------
extern "C" void kernel_launch(void* const* d_in, const int* in_sizes, int n_in,
                              void* d_out, int out_size, void* d_ws, size_t ws_size,
                              hipStream_t stream) {
  (void)in_sizes; (void)n_in; (void)out_size; (void)ws_size;
  const float* x     = (const float*)d_in[0];
  const float* smask = (const float*)d_in[1];
  const float* wqkv  = (const float*)d_in[2];
  const float* bqkv  = (const float*)d_in[3];
  const float* wproj = (const float*)d_in[4];
  const float* bproj = (const float*)d_in[5];
  const float* table = (const float*)d_in[6];
  const float* lng   = (const float*)d_in[7];
  const float* lnb   = (const float*)d_in[8];
  const int*   rpi   = (const int*)d_in[9];
  float* out = (float*)d_out;

  char* ws = (char*)d_ws;
  bf16*  xb   = (bf16*)(ws);                      // 77,070,336 B (live for proj residual)
  bf16*  wqb  = (bf16*)(ws + 77070336);           //  3,538,944 B
  bf16*  wpb  = (bf16*)(ws + 80609280);           //  1,179,648 B
  bf16*  comb = (bf16*)(ws + 81788928);           // 12,582,912 B
  bf16*  qkvT = (bf16*)(ws + 94371840);           // 231,211,008 B
  bf16*  aout = (bf16*)(ws + 325582848);          // 77,070,336 B -> ends 402,653,184
  bf16*  yb   = (bf16*)(ws + 94371840);           // aliases qkvT (dead after attn)

  cvt_bf16<<<37632, 256, 0, stream>>>(x, xb, 9633792);
  cvt_bf16<<<1728, 256, 0, stream>>>(wqkv, wqb, 442368);
  cvt_bf16<<<576, 256, 0, stream>>>(wproj, wpb, 147456);
  build_comb<<<6144, 256, 0, stream>>>(table, rpi, smask, comb);
  qkv_gemm<<<1764, 512, 131072, stream>>>(xb, wqb, bqkv, qkvT);
  attn_kernel<<<dim3(1024, 6), 256, 0, stream>>>(qkvT, comb, aout);
  proj_gemm<<<2352, 256, 0, stream>>>(aout, wpb, bproj, xb, yb);
  ln_kernel<<<12544, 256, 0, stream>>>(yb, lng, lnb, out);
}

// Round 17
// 513.114 us; speedup vs baseline: 1.0447x; 1.0447x over previous
//
#include <hip/hip_runtime.h>
#include <hip/hip_bf16.h>

#define SEQ 49
#define CH 768
#define NH 24
#define HD 32
#define NB 1024
#define NWIN 64
#define MTOT (NB*SEQ)      // 50176

typedef __hip_bfloat16 bf16;
typedef __attribute__((ext_vector_type(8))) short short8;
typedef __attribute__((ext_vector_type(4))) short short4v;
typedef __attribute__((ext_vector_type(4))) float f32x4;

#define MD  ((size_t)MTOT * HD)     // elems per head plane: 1,605,632
#define NHMD ((size_t)NH * MD)      // elems per q/k/v section

__device__ __forceinline__ void gload16(const void* g, void* l) {
  __builtin_amdgcn_global_load_lds((__attribute__((address_space(1))) void*)g,
                                   (__attribute__((address_space(3))) void*)l,
                                   16, 0, 0);
}

__device__ __forceinline__ float bf2f(short s) {
  return __uint_as_float(((unsigned int)(unsigned short)s) << 16);
}

// ---------------- converters ----------------
__global__ void cvt_bf16(const float* __restrict__ in, bf16* __restrict__ o, int n4) {
  int i = blockIdx.x * blockDim.x + threadIdx.x;
  if (i >= n4) return;
  float4 v = ((const float4*)in)[i];
  union { bf16 b[4]; short4 s; } u;
  u.b[0] = __float2bfloat16(v.x);
  u.b[1] = __float2bfloat16(v.y);
  u.b[2] = __float2bfloat16(v.z);
  u.b[3] = __float2bfloat16(v.w);
  ((short4*)o)[i] = u.s;
}

// comb_p[s*24+h][jj][lane][8] (bf16), fragment-ordered, PRE-SCALED by log2(e);
// pads hold -1e30 (exp2 -> 0)
__global__ void build_comb(const float* __restrict__ table, const int* __restrict__ rpi,
                           const float* __restrict__ smask, bf16* __restrict__ comb) {
  int i = blockIdx.x * blockDim.x + threadIdx.x;
  if (i >= NWIN * NH * 1024) return;
  int idx = i * 4;
  int e0 = idx & 7;
  int l = (idx >> 3) & 63;
  int jj = (idx >> 9) & 7;
  int sh = idx >> 12;
  int h = sh % NH;
  int s = sh / NH;
  union { bf16 b[4]; short4 v; } u;
#pragma unroll
  for (int k = 0; k < 4; k++) {
    int j = jj * 8 + e0 + k;
    int mt = j >> 4, nt = (j >> 2) & 3, r = j & 3;
    int m = 16 * mt + 4 * (l >> 4) + r;
    int n = 16 * nt + (l & 15);
    float v = -1e30f;
    if (m < SEQ && n < SEQ)
      v = (table[rpi[m * SEQ + n] * NH + h] + smask[s * SEQ * SEQ + m * SEQ + n])
          * 1.4426950408889634f;
    u.b[k] = __float2bfloat16(v);
  }
  *(short4*)(comb + idx) = u.v;
}

// ---------------- kernel 1: QKV GEMM, 256x256 tile, BK=64 ----------------
// 4 phases/K-tile, counted vmcnt (T4): issue order B0B1|B2B3|A0A2|A1A3,
// entry waits p0:vmcnt(2), p2:vmcnt(4) (last tile: 0). Loads span barriers.
__global__ __launch_bounds__(512) void qkv_gemm(
    const bf16* __restrict__ A, const bf16* __restrict__ Bw,
    const float* __restrict__ bias, bf16* __restrict__ C)
{
  extern __shared__ __align__(16) bf16 lds[];  // [A0|A1|B0|B1] x 16384 elems
  const int tid = threadIdx.x;
  const int w = tid >> 6, l = tid & 63;
  const int lr = l & 15, lg = l >> 4;
  const int wm = w >> 2, wn = w & 3;

  const int flat = blockIdx.x;
  const int xcd = flat & 7, lid = flat >> 3;
  const int wgid = (xcd < 4 ? xcd * 221 : 884 + (xcd - 4) * 220) + lid;
  const int bm = wgid / 9, bn = wgid - 9 * bm;

  const bf16* gA[4];
  const bf16* gB[4];
  int ldst[4];
#pragma unroll
  for (int j = 0; j < 4; j++) {
    int c = j * 512 + tid;
    int row = c >> 3, cpos = c & 7;
    int srcch = cpos ^ (row & 7);
    gA[j] = A + ((size_t)(bm * 256 + row)) * CH + srcch * 8;
    gB[j] = Bw + ((size_t)(bn * 256 + row)) * CH + srcch * 8;
    ldst[j] = c * 8;
  }

  f32x4 acc[8][4];
  f32x4 zero4 = {0.f, 0.f, 0.f, 0.f};
#pragma unroll
  for (int i = 0; i < 8; i++)
#pragma unroll
    for (int j = 0; j < 4; j++) acc[i][j] = zero4;

  int offA[8][2], offB[4][2];
#pragma unroll
  for (int mi = 0; mi < 8; mi++)
#pragma unroll
    for (int ks = 0; ks < 2; ks++) {
      int rowa = wm * 128 + mi * 16 + lr;
      offA[mi][ks] = rowa * 64 + ((lg + 4 * ks) ^ (rowa & 7)) * 8;
    }
#pragma unroll
  for (int nj = 0; nj < 4; nj++)
#pragma unroll
    for (int ks = 0; ks < 2; ks++) {
      int rowb = wn * 64 + nj * 16 + lr;
      offB[nj][ks] = rowb * 64 + ((lg + 4 * ks) ^ (rowb & 7)) * 8;
    }

  // prologue: tile 0 -> buf0, issue order B0,B1,B2,B3,A0,A2,A1,A3
  gload16(gB[0], lds + 32768 + ldst[0]);
  gload16(gB[1], lds + 32768 + ldst[1]);
  gload16(gB[2], lds + 32768 + ldst[2]);
  gload16(gB[3], lds + 32768 + ldst[3]);
  gload16(gA[0], lds + ldst[0]);
  gload16(gA[2], lds + ldst[2]);
  gload16(gA[1], lds + ldst[1]);
  gload16(gA[3], lds + ldst[3]);

  for (int t = 0; t < 12; ++t) {
    const int cur = t & 1;
    const bf16* cA = lds + cur * 16384;
    const bf16* cB = lds + 32768 + cur * 16384;
    bf16* nA = lds + (cur ^ 1) * 16384;
    bf16* nB = lds + 32768 + (cur ^ 1) * 16384;
    const int kk = (t + 1) * 64;
    const bool pf = (t < 11);
#pragma unroll
    for (int p = 0; p < 4; ++p) {
      const int hp = p >> 1, ks = p & 1;
      if (p == 0) {
        asm volatile("s_waitcnt vmcnt(2)" ::: "memory");   // A0,A2,B* of tile t landed
      } else if (p == 2) {
        if (pf) asm volatile("s_waitcnt vmcnt(4)" ::: "memory");  // A1,A3 of tile t landed
        else    asm volatile("s_waitcnt vmcnt(0)" ::: "memory");
      }
      __builtin_amdgcn_sched_barrier(0);
      __builtin_amdgcn_s_barrier();          // propagate per-wave completion CU-wide
      __builtin_amdgcn_sched_barrier(0);
      short8 af[4], bfv[4];
#pragma unroll
      for (int mi = 0; mi < 4; mi++) af[mi] = *(const short8*)(cA + offA[hp * 4 + mi][ks]);
#pragma unroll
      for (int nj = 0; nj < 4; nj++) bfv[nj] = *(const short8*)(cB + offB[nj][ks]);
      if (pf) {
        if (p == 0) { gload16(gB[0] + kk, nB + ldst[0]); gload16(gB[1] + kk, nB + ldst[1]); }
        if (p == 1) { gload16(gB[2] + kk, nB + ldst[2]); gload16(gB[3] + kk, nB + ldst[3]); }
        if (p == 2) { gload16(gA[0] + kk, nA + ldst[0]); gload16(gA[2] + kk, nA + ldst[2]); }
        if (p == 3) { gload16(gA[1] + kk, nA + ldst[1]); gload16(gA[3] + kk, nA + ldst[3]); }
      }
      asm volatile("s_waitcnt lgkmcnt(0)" ::: "memory");
      __builtin_amdgcn_sched_barrier(0);
      __builtin_amdgcn_s_setprio(1);
#pragma unroll
      for (int mi = 0; mi < 4; mi++)
#pragma unroll
        for (int nj = 0; nj < 4; nj++)
          acc[hp * 4 + mi][nj] =
              __builtin_amdgcn_mfma_f32_16x16x32_bf16(af[mi], bfv[nj], acc[hp * 4 + mi][nj], 0, 0, 0);
      __builtin_amdgcn_s_setprio(0);
    }
  }

  const float scale = 0.25503487724583985f;  // log2(e)/sqrt(32)
  const int colbase = bn * 256 + 64 * wn;
  const int rowbase = bm * 256 + 128 * wm;
#pragma unroll
  for (int nj = 0; nj < 4; nj++) {
    const int cb16 = colbase + 16 * nj;
    const int sec = cb16 / 768;              // 0=q 1=k 2=v
    const int rem = cb16 - sec * 768;
    const int h = rem >> 5;
    const int dbase = rem & 31;              // 0 or 16
    float bv = bias[cb16 + lr];
    if (sec == 2) {
      const size_t vbase = 2 * NHMD + ((size_t)h * HD + dbase + lr) * MTOT;
#pragma unroll
      for (int mi = 0; mi < 8; mi++) {
        size_t row = rowbase + 16 * mi + 4 * lg;
        union { bf16 b[4]; short4 s; } u;
#pragma unroll
        for (int r = 0; r < 4; r++) u.b[r] = __float2bfloat16(acc[mi][nj][r] + bv);
        *(short4*)(C + vbase + row) = u.s;
      }
    } else {
      const float mul = (sec == 0) ? scale : 1.0f;
      const size_t base = (size_t)sec * NHMD + (size_t)h * MD + dbase + lr;
#pragma unroll
      for (int mi = 0; mi < 8; mi++) {
#pragma unroll
        for (int r = 0; r < 4; r++) {
          size_t row = rowbase + 16 * mi + 4 * lg + r;
          C[base + row * HD] = __float2bfloat16((acc[mi][nj][r] + bv) * mul);
        }
      }
    }
  }
}

// ---------------- kernel 2: attention (per-mt phased, 4 waves/SIMD) ----------------
__global__ __launch_bounds__(256, 4) void attn_kernel(
    const bf16* __restrict__ qkvT, const bf16* __restrict__ comb,
    bf16* __restrict__ aout)
{
  __shared__ __align__(16) bf16 P[4][64 * 72];
  const int tid = threadIdx.x;
  const int w = tid >> 6, l = tid & 63;
  const int lr = l & 15, lg = l >> 4;
  const int b = blockIdx.x;
  const int h = blockIdx.y * 4 + w;
  const size_t rowb = (size_t)b * SEQ;
  f32x4 zero4 = {0.f, 0.f, 0.f, 0.f};

  const bf16* qb = qkvT + (size_t)h * MD + rowb * HD;          // q pre-scaled (log2e/sqrt32)
  const bf16* kb = qkvT + NHMD + (size_t)h * MD + rowb * HD;
  const bf16* vT = qkvT + 2 * NHMD + (size_t)h * HD * MTOT;    // [32][M]

  short8 kf[4];
#pragma unroll
  for (int nt = 0; nt < 4; nt++)
    kf[nt] = *(const short8*)(kb + (16 * nt + lr) * HD + 8 * lg);

  short8 pb[2][2];
#pragma unroll
  for (int kt = 0; kt < 2; kt++)
#pragma unroll
    for (int dt = 0; dt < 2; dt++)
      pb[kt][dt] = *(const short8*)(vT + ((size_t)(16 * dt + lr)) * MTOT + rowb + 32 * kt + 8 * lg);

  const bf16* cbp = comb + (((size_t)(b & (NWIN - 1)) * NH + h) << 12);
  float inv[4][4];

#pragma unroll
  for (int mt = 0; mt < 4; mt++) {
    short8 qf = *(const short8*)(qb + (16 * mt + lr) * HD + 8 * lg);
    f32x4 s4[4];
#pragma unroll
    for (int nt = 0; nt < 4; nt++)
      s4[nt] = __builtin_amdgcn_mfma_f32_16x16x32_bf16(qf, kf[nt], zero4, 0, 0, 0);
    short8 c0 = *(const short8*)(cbp + ((2 * mt) * 64 + l) * 8);
    short8 c1 = *(const short8*)(cbp + ((2 * mt + 1) * 64 + l) * 8);
#pragma unroll
    for (int e = 0; e < 8; e++) s4[e >> 2][e & 3] += bf2f(c0[e]);
#pragma unroll
    for (int e = 0; e < 8; e++) s4[2 + (e >> 2)][e & 3] += bf2f(c1[e]);
#pragma unroll
    for (int r = 0; r < 4; r++) {
      float t = 0.f;
#pragma unroll
      for (int nt = 0; nt < 4; nt++) {
        float e = exp2f(s4[nt][r]);
        s4[nt][r] = e;
        t += e;
      }
      t += __shfl_xor(t, 1, 64);
      t += __shfl_xor(t, 2, 64);
      t += __shfl_xor(t, 4, 64);
      t += __shfl_xor(t, 8, 64);
      inv[mt][r] = 1.0f / t;
    }
#pragma unroll
    for (int nt = 0; nt < 4; nt++)
#pragma unroll
      for (int r = 0; r < 4; r++)
        P[w][(16 * mt + 4 * lg + r) * 72 + 16 * nt + lr] = __float2bfloat16(s4[nt][r]);
  }

  f32x4 o[4][2];
#pragma unroll
  for (int mt = 0; mt < 4; mt++) { o[mt][0] = zero4; o[mt][1] = zero4; }
#pragma unroll
  for (int kt = 0; kt < 2; kt++) {
    short8 pa[4];
#pragma unroll
    for (int mt = 0; mt < 4; mt++)
      pa[mt] = *(const short8*)(&P[w][(16 * mt + lr) * 72 + 32 * kt + 8 * lg]);
#pragma unroll
    for (int mt = 0; mt < 4; mt++)
#pragma unroll
      for (int dt = 0; dt < 2; dt++)
        o[mt][dt] = __builtin_amdgcn_mfma_f32_16x16x32_bf16(pa[mt], pb[kt][dt], o[mt][dt], 0, 0, 0);
  }

#pragma unroll
  for (int mt = 0; mt < 4; mt++)
#pragma unroll
    for (int dt = 0; dt < 2; dt++)
#pragma unroll
      for (int r = 0; r < 4; r++) {
        int m = 16 * mt + 4 * lg + r;
        if (m < SEQ)
          aout[(rowb + m) * CH + h * HD + 16 * dt + lr] =
              __float2bfloat16(o[mt][dt][r] * inv[mt][r]);
      }
}

// ---------------- kernel 3: proj GEMM + bias + residual(bf16), 2-phase ----------------
// all 8 prefetches issued in phase 0 -> wider latency window before entry wait.
__global__ __launch_bounds__(256) void proj_gemm(
    const bf16* __restrict__ A, const bf16* __restrict__ Bw,
    const float* __restrict__ bias, const bf16* __restrict__ xb,
    bf16* __restrict__ Y)
{
  __shared__ __align__(16) bf16 As[2 * 128 * 64];
  __shared__ __align__(16) bf16 Bs[2 * 128 * 64];
  const int tid = threadIdx.x;
  const int w = tid >> 6, l = tid & 63;
  const int lr = l & 15, lg = l >> 4;
  const int wm = w >> 1, wn = w & 1;

  const int flat = blockIdx.x;                 // 2352 = 8 x 294
  const int wg = (flat & 7) * 294 + (flat >> 3);
  const int bm = wg / 6, bn = wg - 6 * (wg / 6);

  const bf16* gA[4];
  const bf16* gB[4];
  int ldst[4];
#pragma unroll
  for (int j = 0; j < 4; j++) {
    int c = j * 256 + tid;
    int row = c >> 3, cpos = c & 7;
    int srcch = cpos ^ (row & 7);
    gA[j] = A + ((size_t)(bm * 128 + row)) * CH + srcch * 8;
    gB[j] = Bw + ((size_t)(bn * 128 + row)) * CH + srcch * 8;
    ldst[j] = c * 8;
  }

  f32x4 acc[4][4];
  f32x4 zero4 = {0.f, 0.f, 0.f, 0.f};
#pragma unroll
  for (int i = 0; i < 4; i++)
#pragma unroll
    for (int j = 0; j < 4; j++) acc[i][j] = zero4;

  int offA[4][2], offB[4][2];
#pragma unroll
  for (int mi = 0; mi < 4; mi++) {
#pragma unroll
    for (int ks = 0; ks < 2; ks++) {
      int rowa = 64 * wm + 16 * mi + lr;
      offA[mi][ks] = rowa * 64 + ((lg + 4 * ks) ^ (rowa & 7)) * 8;
      int rowb = 64 * wn + 16 * mi + lr;
      offB[mi][ks] = rowb * 64 + ((lg + 4 * ks) ^ (rowb & 7)) * 8;
    }
  }

#pragma unroll
  for (int j = 0; j < 4; j++) gload16(gA[j], As + ldst[j]);
#pragma unroll
  for (int j = 0; j < 4; j++) gload16(gB[j], Bs + ldst[j]);

  for (int t = 0; t < 12; ++t) {
    const int base = (t & 1) * 8192;
    asm volatile("s_waitcnt vmcnt(0)" ::: "memory");
    __builtin_amdgcn_sched_barrier(0);
    __builtin_amdgcn_s_barrier();
    __builtin_amdgcn_sched_barrier(0);
    const bf16* cA = As + base;
    const bf16* cB = Bs + base;
    bf16* nA = As + (base ^ 8192);
    bf16* nB = Bs + (base ^ 8192);
    const int kk = (t + 1) * 64;
    const bool pf = (t < 11);
#pragma unroll
    for (int ks = 0; ks < 2; ks++) {
      short8 af[4], bfv[4];
#pragma unroll
      for (int mi = 0; mi < 4; mi++) {
        af[mi] = *(const short8*)(cA + offA[mi][ks]);
        bfv[mi] = *(const short8*)(cB + offB[mi][ks]);
      }
      if (pf && ks == 0) {
#pragma unroll
        for (int j = 0; j < 4; j++) {
          gload16(gA[j] + kk, nA + ldst[j]);
          gload16(gB[j] + kk, nB + ldst[j]);
        }
      }
      asm volatile("s_waitcnt lgkmcnt(0)" ::: "memory");
      __builtin_amdgcn_sched_barrier(0);
      __builtin_amdgcn_s_setprio(1);
#pragma unroll
      for (int mi = 0; mi < 4; mi++)
#pragma unroll
        for (int nj = 0; nj < 4; nj++)
          acc[mi][nj] = __builtin_amdgcn_mfma_f32_16x16x32_bf16(af[mi], bfv[nj], acc[mi][nj], 0, 0, 0);
      __builtin_amdgcn_s_setprio(0);
    }
  }

  const int colbase = bn * 128 + 64 * wn;
  const int rowbase = bm * 128 + 64 * wm;
#pragma unroll
  for (int nj = 0; nj < 4; nj++) {
    int col = colbase + 16 * nj + lr;
    float bv = bias[col];
#pragma unroll
    for (int mi = 0; mi < 4; mi++) {
#pragma unroll
      for (int r = 0; r < 4; r++) {
        size_t row = rowbase + 16 * mi + 4 * lg + r;
        float v = acc[mi][nj][r] + bv + bf2f(((const short*)xb)[row * CH + col]);
        Y[row * CH + col] = __float2bfloat16(v);
      }
    }
  }
}

// ---------------- kernel 4: LayerNorm ----------------
__global__ __launch_bounds__(256) void ln_kernel(
    const bf16* __restrict__ Y, const float* __restrict__ g,
    const float* __restrict__ be, float* __restrict__ out)
{
  const int w = threadIdx.x >> 6, l = threadIdx.x & 63;
  const size_t r = (size_t)blockIdx.x * 4 + w;
  const bf16* yr = Y + r * CH;

  short8 a = *(const short8*)(yr + 8 * l);
  short4v b4 = *(const short4v*)(yr + 512 + 4 * l);
  float v[12];
#pragma unroll
  for (int j = 0; j < 8; j++) v[j] = bf2f(a[j]);
#pragma unroll
  for (int j = 0; j < 4; j++) v[8 + j] = bf2f(b4[j]);

  float s1 = 0.f, s2 = 0.f;
#pragma unroll
  for (int j = 0; j < 12; j++) { s1 += v[j]; s2 += v[j] * v[j]; }
#pragma unroll
  for (int m = 1; m <= 32; m <<= 1) {
    s1 += __shfl_xor(s1, m, 64);
    s2 += __shfl_xor(s2, m, 64);
  }
  float mu = s1 * (1.0f / 768.0f);
  float var = s2 * (1.0f / 768.0f) - mu * mu;
  float rs = rsqrtf(var + 1e-5f);

  float4 g0 = *(const float4*)(g + 8 * l);
  float4 g1 = *(const float4*)(g + 8 * l + 4);
  float4 g2 = *(const float4*)(g + 512 + 4 * l);
  float4 b0 = *(const float4*)(be + 8 * l);
  float4 b1 = *(const float4*)(be + 8 * l + 4);
  float4 b2 = *(const float4*)(be + 512 + 4 * l);

  float4 o0, o1, o2;
  o0.x = (v[0] - mu) * rs * g0.x + b0.x;
  o0.y = (v[1] - mu) * rs * g0.y + b0.y;
  o0.z = (v[2] - mu) * rs * g0.z + b0.z;
  o0.w = (v[3] - mu) * rs * g0.w + b0.w;
  o1.x = (v[4] - mu) * rs * g1.x + b1.x;
  o1.y = (v[5] - mu) * rs * g1.y + b1.y;
  o1.z = (v[6] - mu) * rs * g1.z + b1.z;
  o1.w = (v[7] - mu) * rs * g1.w + b1.w;
  o2.x = (v[8] - mu) * rs * g2.x + b2.x;
  o2.y = (v[9] - mu) * rs * g2.y + b2.y;
  o2.z = (v[10] - mu) * rs * g2.z + b2.z;
  o2.w = (v[11] - mu) * rs * g2.w + b2.w;

  float* orow = out + r * CH;
  *(float4*)(orow + 8 * l) = o0;
  *(float4*)(orow + 8 * l + 4) = o1;
  *(float4*)(orow + 512 + 4 * l) = o2;
}

// ---------------- launch ----------------
extern "C" void kernel_launch(void* const* d_in, const int* in_sizes, int n_in,
                              void* d_out, int out_size, void* d_ws, size_t ws_size,
                              hipStream_t stream) {
  (void)in_sizes; (void)n_in; (void)out_size; (void)ws_size;
  const float* x     = (const float*)d_in[0];
  const float* smask = (const float*)d_in[1];
  const float* wqkv  = (const float*)d_in[2];
  const float* bqkv  = (const float*)d_in[3];
  const float* wproj = (const float*)d_in[4];
  const float* bproj = (const float*)d_in[5];
  const float* table = (const float*)d_in[6];
  const float* lng   = (const float*)d_in[7];
  const float* lnb   = (const float*)d_in[8];
  const int*   rpi   = (const int*)d_in[9];
  float* out = (float*)d_out;

  char* ws = (char*)d_ws;
  bf16*  xb   = (bf16*)(ws);                      // 77,070,336 B (live for proj residual)
  bf16*  wqb  = (bf16*)(ws + 77070336);           //  3,538,944 B
  bf16*  wpb  = (bf16*)(ws + 80609280);           //  1,179,648 B
  bf16*  comb = (bf16*)(ws + 81788928);           // 12,582,912 B
  bf16*  qkvT = (bf16*)(ws + 94371840);           // 231,211,008 B
  bf16*  aout = (bf16*)(ws + 325582848);          // 77,070,336 B -> ends 402,653,184
  bf16*  yb   = (bf16*)(ws + 94371840);           // aliases qkvT (dead after attn)

  cvt_bf16<<<37632, 256, 0, stream>>>(x, xb, 9633792);
  cvt_bf16<<<1728, 256, 0, stream>>>(wqkv, wqb, 442368);
  cvt_bf16<<<576, 256, 0, stream>>>(wproj, wpb, 147456);
  build_comb<<<6144, 256, 0, stream>>>(table, rpi, smask, comb);
  qkv_gemm<<<1764, 512, 131072, stream>>>(xb, wqb, bqkv, qkvT);
  attn_kernel<<<dim3(1024, 6), 256, 0, stream>>>(qkvT, comb, aout);
  proj_gemm<<<2352, 256, 0, stream>>>(aout, wpb, bproj, xb, yb);
  ln_kernel<<<12544, 256, 0, stream>>>(yb, lng, lnb, out);
}

// Round 18
// 506.749 us; speedup vs baseline: 1.0578x; 1.0126x over previous
//
#include <hip/hip_runtime.h>
#include <hip/hip_bf16.h>

#define SEQ 49
#define CH 768
#define NH 24
#define HD 32
#define NB 1024
#define NWIN 64
#define MTOT (NB*SEQ)      // 50176

typedef __hip_bfloat16 bf16;
typedef __attribute__((ext_vector_type(8))) short short8;
typedef __attribute__((ext_vector_type(4))) short short4v;
typedef __attribute__((ext_vector_type(4))) float f32x4;

#define MD  ((size_t)MTOT * HD)     // elems per head plane: 1,605,632
#define NHMD ((size_t)NH * MD)      // elems per q/k/v section

__device__ __forceinline__ void gload16(const void* g, void* l) {
  __builtin_amdgcn_global_load_lds((__attribute__((address_space(1))) void*)g,
                                   (__attribute__((address_space(3))) void*)l,
                                   16, 0, 0);
}

__device__ __forceinline__ float bf2f(short s) {
  return __uint_as_float(((unsigned int)(unsigned short)s) << 16);
}

// ---------------- converters ----------------
__global__ void cvt_bf16(const float* __restrict__ in, bf16* __restrict__ o, int n4) {
  int i = blockIdx.x * blockDim.x + threadIdx.x;
  if (i >= n4) return;
  float4 v = ((const float4*)in)[i];
  union { bf16 b[4]; short4 s; } u;
  u.b[0] = __float2bfloat16(v.x);
  u.b[1] = __float2bfloat16(v.y);
  u.b[2] = __float2bfloat16(v.z);
  u.b[3] = __float2bfloat16(v.w);
  ((short4*)o)[i] = u.s;
}

// comb_p[s*24+h][jj][lane][8] (bf16), fragment-ordered, PRE-SCALED by log2(e);
// pads hold -1e30 (exp2 -> 0)
__global__ void build_comb(const float* __restrict__ table, const int* __restrict__ rpi,
                           const float* __restrict__ smask, bf16* __restrict__ comb) {
  int i = blockIdx.x * blockDim.x + threadIdx.x;
  if (i >= NWIN * NH * 1024) return;
  int idx = i * 4;
  int e0 = idx & 7;
  int l = (idx >> 3) & 63;
  int jj = (idx >> 9) & 7;
  int sh = idx >> 12;
  int h = sh % NH;
  int s = sh / NH;
  union { bf16 b[4]; short4 v; } u;
#pragma unroll
  for (int k = 0; k < 4; k++) {
    int j = jj * 8 + e0 + k;
    int mt = j >> 4, nt = (j >> 2) & 3, r = j & 3;
    int m = 16 * mt + 4 * (l >> 4) + r;
    int n = 16 * nt + (l & 15);
    float v = -1e30f;
    if (m < SEQ && n < SEQ)
      v = (table[rpi[m * SEQ + n] * NH + h] + smask[s * SEQ * SEQ + m * SEQ + n])
          * 1.4426950408889634f;
    u.b[k] = __float2bfloat16(v);
  }
  *(short4*)(comb + idx) = u.v;
}

// ---------------- kernel 1: QKV GEMM, 256x256 tile, BK=64 ----------------
// 4 phases/K-tile, counted vmcnt (T4): issue order B0B1|B2B3|A0A2|A1A3,
// entry waits p0:vmcnt(2), p2:vmcnt(4) (last tile: 0). Loads span barriers.
__global__ __launch_bounds__(512) void qkv_gemm(
    const bf16* __restrict__ A, const bf16* __restrict__ Bw,
    const float* __restrict__ bias, bf16* __restrict__ C)
{
  extern __shared__ __align__(16) bf16 lds[];  // [A0|A1|B0|B1] x 16384 elems
  const int tid = threadIdx.x;
  const int w = tid >> 6, l = tid & 63;
  const int lr = l & 15, lg = l >> 4;
  const int wm = w >> 2, wn = w & 3;

  const int flat = blockIdx.x;
  const int xcd = flat & 7, lid = flat >> 3;
  const int wgid = (xcd < 4 ? xcd * 221 : 884 + (xcd - 4) * 220) + lid;
  const int bm = wgid / 9, bn = wgid - 9 * bm;

  const bf16* gA[4];
  const bf16* gB[4];
  int ldst[4];
#pragma unroll
  for (int j = 0; j < 4; j++) {
    int c = j * 512 + tid;
    int row = c >> 3, cpos = c & 7;
    int srcch = cpos ^ (row & 7);
    gA[j] = A + ((size_t)(bm * 256 + row)) * CH + srcch * 8;
    gB[j] = Bw + ((size_t)(bn * 256 + row)) * CH + srcch * 8;
    ldst[j] = c * 8;
  }

  f32x4 acc[8][4];
  f32x4 zero4 = {0.f, 0.f, 0.f, 0.f};
#pragma unroll
  for (int i = 0; i < 8; i++)
#pragma unroll
    for (int j = 0; j < 4; j++) acc[i][j] = zero4;

  int offA[8][2], offB[4][2];
#pragma unroll
  for (int mi = 0; mi < 8; mi++)
#pragma unroll
    for (int ks = 0; ks < 2; ks++) {
      int rowa = wm * 128 + mi * 16 + lr;
      offA[mi][ks] = rowa * 64 + ((lg + 4 * ks) ^ (rowa & 7)) * 8;
    }
#pragma unroll
  for (int nj = 0; nj < 4; nj++)
#pragma unroll
    for (int ks = 0; ks < 2; ks++) {
      int rowb = wn * 64 + nj * 16 + lr;
      offB[nj][ks] = rowb * 64 + ((lg + 4 * ks) ^ (rowb & 7)) * 8;
    }

  // prologue: tile 0 -> buf0, issue order B0,B1,B2,B3,A0,A2,A1,A3
  gload16(gB[0], lds + 32768 + ldst[0]);
  gload16(gB[1], lds + 32768 + ldst[1]);
  gload16(gB[2], lds + 32768 + ldst[2]);
  gload16(gB[3], lds + 32768 + ldst[3]);
  gload16(gA[0], lds + ldst[0]);
  gload16(gA[2], lds + ldst[2]);
  gload16(gA[1], lds + ldst[1]);
  gload16(gA[3], lds + ldst[3]);

  for (int t = 0; t < 12; ++t) {
    const int cur = t & 1;
    const bf16* cA = lds + cur * 16384;
    const bf16* cB = lds + 32768 + cur * 16384;
    bf16* nA = lds + (cur ^ 1) * 16384;
    bf16* nB = lds + 32768 + (cur ^ 1) * 16384;
    const int kk = (t + 1) * 64;
    const bool pf = (t < 11);
#pragma unroll
    for (int p = 0; p < 4; ++p) {
      const int hp = p >> 1, ks = p & 1;
      if (p == 0) {
        asm volatile("s_waitcnt vmcnt(2)" ::: "memory");   // A0,A2,B* of tile t landed
      } else if (p == 2) {
        if (pf) asm volatile("s_waitcnt vmcnt(4)" ::: "memory");  // A1,A3 of tile t landed
        else    asm volatile("s_waitcnt vmcnt(0)" ::: "memory");
      }
      __builtin_amdgcn_sched_barrier(0);
      __builtin_amdgcn_s_barrier();          // propagate per-wave completion CU-wide
      __builtin_amdgcn_sched_barrier(0);
      short8 af[4], bfv[4];
#pragma unroll
      for (int mi = 0; mi < 4; mi++) af[mi] = *(const short8*)(cA + offA[hp * 4 + mi][ks]);
#pragma unroll
      for (int nj = 0; nj < 4; nj++) bfv[nj] = *(const short8*)(cB + offB[nj][ks]);
      if (pf) {
        if (p == 0) { gload16(gB[0] + kk, nB + ldst[0]); gload16(gB[1] + kk, nB + ldst[1]); }
        if (p == 1) { gload16(gB[2] + kk, nB + ldst[2]); gload16(gB[3] + kk, nB + ldst[3]); }
        if (p == 2) { gload16(gA[0] + kk, nA + ldst[0]); gload16(gA[2] + kk, nA + ldst[2]); }
        if (p == 3) { gload16(gA[1] + kk, nA + ldst[1]); gload16(gA[3] + kk, nA + ldst[3]); }
      }
      asm volatile("s_waitcnt lgkmcnt(0)" ::: "memory");
      __builtin_amdgcn_sched_barrier(0);
      __builtin_amdgcn_s_setprio(1);
#pragma unroll
      for (int mi = 0; mi < 4; mi++)
#pragma unroll
        for (int nj = 0; nj < 4; nj++)
          acc[hp * 4 + mi][nj] =
              __builtin_amdgcn_mfma_f32_16x16x32_bf16(af[mi], bfv[nj], acc[hp * 4 + mi][nj], 0, 0, 0);
      __builtin_amdgcn_s_setprio(0);
    }
  }

  const float scale = 0.25503487724583985f;  // log2(e)/sqrt(32)
  const int colbase = bn * 256 + 64 * wn;
  const int rowbase = bm * 256 + 128 * wm;
#pragma unroll
  for (int nj = 0; nj < 4; nj++) {
    const int cb16 = colbase + 16 * nj;
    const int sec = cb16 / 768;              // 0=q 1=k 2=v
    const int rem = cb16 - sec * 768;
    const int h = rem >> 5;
    const int dbase = rem & 31;              // 0 or 16
    float bv = bias[cb16 + lr];
    if (sec == 2) {
      const size_t vbase = 2 * NHMD + ((size_t)h * HD + dbase + lr) * MTOT;
#pragma unroll
      for (int mi = 0; mi < 8; mi++) {
        size_t row = rowbase + 16 * mi + 4 * lg;
        union { bf16 b[4]; short4 s; } u;
#pragma unroll
        for (int r = 0; r < 4; r++) u.b[r] = __float2bfloat16(acc[mi][nj][r] + bv);
        *(short4*)(C + vbase + row) = u.s;
      }
    } else {
      const float mul = (sec == 0) ? scale : 1.0f;
      const size_t base = (size_t)sec * NHMD + (size_t)h * MD + dbase + lr;
#pragma unroll
      for (int mi = 0; mi < 8; mi++) {
#pragma unroll
        for (int r = 0; r < 4; r++) {
          size_t row = rowbase + 16 * mi + 4 * lg + r;
          C[base + row * HD] = __float2bfloat16((acc[mi][nj][r] + bv) * mul);
        }
      }
    }
  }
}

// ---------------- kernel 2: attention (per-mt phased, 4 waves/SIMD) ----------------
// aout now head-plane layout [h][M][32]: each (wave,mt) writes dense 1 KB.
__global__ __launch_bounds__(256, 4) void attn_kernel(
    const bf16* __restrict__ qkvT, const bf16* __restrict__ comb,
    bf16* __restrict__ aoutP)
{
  __shared__ __align__(16) bf16 P[4][64 * 72];
  const int tid = threadIdx.x;
  const int w = tid >> 6, l = tid & 63;
  const int lr = l & 15, lg = l >> 4;
  const int b = blockIdx.x;
  const int h = blockIdx.y * 4 + w;
  const size_t rowb = (size_t)b * SEQ;
  f32x4 zero4 = {0.f, 0.f, 0.f, 0.f};

  const bf16* qb = qkvT + (size_t)h * MD + rowb * HD;          // q pre-scaled (log2e/sqrt32)
  const bf16* kb = qkvT + NHMD + (size_t)h * MD + rowb * HD;
  const bf16* vT = qkvT + 2 * NHMD + (size_t)h * HD * MTOT;    // [32][M]
  bf16* ao = aoutP + (size_t)h * MD + rowb * HD;               // [h][M][32] plane

  short8 kf[4];
#pragma unroll
  for (int nt = 0; nt < 4; nt++)
    kf[nt] = *(const short8*)(kb + (16 * nt + lr) * HD + 8 * lg);

  short8 pb[2][2];
#pragma unroll
  for (int kt = 0; kt < 2; kt++)
#pragma unroll
    for (int dt = 0; dt < 2; dt++)
      pb[kt][dt] = *(const short8*)(vT + ((size_t)(16 * dt + lr)) * MTOT + rowb + 32 * kt + 8 * lg);

  const bf16* cbp = comb + (((size_t)(b & (NWIN - 1)) * NH + h) << 12);
  float inv[4][4];

#pragma unroll
  for (int mt = 0; mt < 4; mt++) {
    short8 qf = *(const short8*)(qb + (16 * mt + lr) * HD + 8 * lg);
    f32x4 s4[4];
#pragma unroll
    for (int nt = 0; nt < 4; nt++)
      s4[nt] = __builtin_amdgcn_mfma_f32_16x16x32_bf16(qf, kf[nt], zero4, 0, 0, 0);
    short8 c0 = *(const short8*)(cbp + ((2 * mt) * 64 + l) * 8);
    short8 c1 = *(const short8*)(cbp + ((2 * mt + 1) * 64 + l) * 8);
#pragma unroll
    for (int e = 0; e < 8; e++) s4[e >> 2][e & 3] += bf2f(c0[e]);
#pragma unroll
    for (int e = 0; e < 8; e++) s4[2 + (e >> 2)][e & 3] += bf2f(c1[e]);
#pragma unroll
    for (int r = 0; r < 4; r++) {
      float t = 0.f;
#pragma unroll
      for (int nt = 0; nt < 4; nt++) {
        float e = exp2f(s4[nt][r]);
        s4[nt][r] = e;
        t += e;
      }
      t += __shfl_xor(t, 1, 64);
      t += __shfl_xor(t, 2, 64);
      t += __shfl_xor(t, 4, 64);
      t += __shfl_xor(t, 8, 64);
      inv[mt][r] = 1.0f / t;
    }
#pragma unroll
    for (int nt = 0; nt < 4; nt++)
#pragma unroll
      for (int r = 0; r < 4; r++)
        P[w][(16 * mt + 4 * lg + r) * 72 + 16 * nt + lr] = __float2bfloat16(s4[nt][r]);
  }

  f32x4 o[4][2];
#pragma unroll
  for (int mt = 0; mt < 4; mt++) { o[mt][0] = zero4; o[mt][1] = zero4; }
#pragma unroll
  for (int kt = 0; kt < 2; kt++) {
    short8 pa[4];
#pragma unroll
    for (int mt = 0; mt < 4; mt++)
      pa[mt] = *(const short8*)(&P[w][(16 * mt + lr) * 72 + 32 * kt + 8 * lg]);
#pragma unroll
    for (int mt = 0; mt < 4; mt++)
#pragma unroll
      for (int dt = 0; dt < 2; dt++)
        o[mt][dt] = __builtin_amdgcn_mfma_f32_16x16x32_bf16(pa[mt], pb[kt][dt], o[mt][dt], 0, 0, 0);
  }

#pragma unroll
  for (int mt = 0; mt < 4; mt++)
#pragma unroll
    for (int dt = 0; dt < 2; dt++)
#pragma unroll
      for (int r = 0; r < 4; r++) {
        int m = 16 * mt + 4 * lg + r;
        if (m < SEQ)
          ao[(size_t)m * HD + 16 * dt + lr] =
              __float2bfloat16(o[mt][dt][r] * inv[mt][r]);
      }
}

// ---------------- kernel 3: proj GEMM + bias + residual(bf16), 2-phase ----------------
// A operand read from head-plane layout [h][M][32]; K-tile advance = 2*MD elems.
__global__ __launch_bounds__(256) void proj_gemm(
    const bf16* __restrict__ Ap, const bf16* __restrict__ Bw,
    const float* __restrict__ bias, const bf16* __restrict__ xb,
    bf16* __restrict__ Y)
{
  __shared__ __align__(16) bf16 As[2 * 128 * 64];
  __shared__ __align__(16) bf16 Bs[2 * 128 * 64];
  const int tid = threadIdx.x;
  const int w = tid >> 6, l = tid & 63;
  const int lr = l & 15, lg = l >> 4;
  const int wm = w >> 1, wn = w & 1;

  const int flat = blockIdx.x;                 // 2352 = 8 x 294
  const int wg = (flat & 7) * 294 + (flat >> 3);
  const int bm = wg / 6, bn = wg - 6 * (wg / 6);

  const bf16* gA[4];
  const bf16* gB[4];
  int ldst[4];
#pragma unroll
  for (int j = 0; j < 4; j++) {
    int c = j * 256 + tid;
    int row = c >> 3, cpos = c & 7;
    int srcch = cpos ^ (row & 7);
    int col0 = srcch * 8;                      // 0..63 within first 2 head planes
    gA[j] = Ap + (size_t)(col0 >> 5) * MD + ((size_t)(bm * 128 + row)) * HD + (col0 & 31);
    gB[j] = Bw + ((size_t)(bn * 128 + row)) * CH + srcch * 8;
    ldst[j] = c * 8;
  }

  f32x4 acc[4][4];
  f32x4 zero4 = {0.f, 0.f, 0.f, 0.f};
#pragma unroll
  for (int i = 0; i < 4; i++)
#pragma unroll
    for (int j = 0; j < 4; j++) acc[i][j] = zero4;

  int offA[4][2], offB[4][2];
#pragma unroll
  for (int mi = 0; mi < 4; mi++) {
#pragma unroll
    for (int ks = 0; ks < 2; ks++) {
      int rowa = 64 * wm + 16 * mi + lr;
      offA[mi][ks] = rowa * 64 + ((lg + 4 * ks) ^ (rowa & 7)) * 8;
      int rowb = 64 * wn + 16 * mi + lr;
      offB[mi][ks] = rowb * 64 + ((lg + 4 * ks) ^ (rowb & 7)) * 8;
    }
  }

#pragma unroll
  for (int j = 0; j < 4; j++) gload16(gA[j], As + ldst[j]);
#pragma unroll
  for (int j = 0; j < 4; j++) gload16(gB[j], Bs + ldst[j]);

  for (int t = 0; t < 12; ++t) {
    const int base = (t & 1) * 8192;
    asm volatile("s_waitcnt vmcnt(0)" ::: "memory");
    __builtin_amdgcn_sched_barrier(0);
    __builtin_amdgcn_s_barrier();
    __builtin_amdgcn_sched_barrier(0);
    const bf16* cA = As + base;
    const bf16* cB = Bs + base;
    bf16* nA = As + (base ^ 8192);
    bf16* nB = Bs + (base ^ 8192);
    const int kk = (t + 1) * 64;               // B advance (row-major)
    const size_t ka = (size_t)(t + 1) * 2 * MD; // A advance (2 head planes/tile)
    const bool pf = (t < 11);
#pragma unroll
    for (int ks = 0; ks < 2; ks++) {
      short8 af[4], bfv[4];
#pragma unroll
      for (int mi = 0; mi < 4; mi++) {
        af[mi] = *(const short8*)(cA + offA[mi][ks]);
        bfv[mi] = *(const short8*)(cB + offB[mi][ks]);
      }
      if (pf && ks == 0) {
#pragma unroll
        for (int j = 0; j < 4; j++) {
          gload16(gA[j] + ka, nA + ldst[j]);
          gload16(gB[j] + kk, nB + ldst[j]);
        }
      }
      asm volatile("s_waitcnt lgkmcnt(0)" ::: "memory");
      __builtin_amdgcn_sched_barrier(0);
      __builtin_amdgcn_s_setprio(1);
#pragma unroll
      for (int mi = 0; mi < 4; mi++)
#pragma unroll
        for (int nj = 0; nj < 4; nj++)
          acc[mi][nj] = __builtin_amdgcn_mfma_f32_16x16x32_bf16(af[mi], bfv[nj], acc[mi][nj], 0, 0, 0);
      __builtin_amdgcn_s_setprio(0);
    }
  }

  const int colbase = bn * 128 + 64 * wn;
  const int rowbase = bm * 128 + 64 * wm;
#pragma unroll
  for (int nj = 0; nj < 4; nj++) {
    int col = colbase + 16 * nj + lr;
    float bv = bias[col];
#pragma unroll
    for (int mi = 0; mi < 4; mi++) {
#pragma unroll
      for (int r = 0; r < 4; r++) {
        size_t row = rowbase + 16 * mi + 4 * lg + r;
        float v = acc[mi][nj][r] + bv + bf2f(((const short*)xb)[row * CH + col]);
        Y[row * CH + col] = __float2bfloat16(v);
      }
    }
  }
}

// ---------------- kernel 4: LayerNorm ----------------
__global__ __launch_bounds__(256) void ln_kernel(
    const bf16* __restrict__ Y, const float* __restrict__ g,
    const float* __restrict__ be, float* __restrict__ out)
{
  const int w = threadIdx.x >> 6, l = threadIdx.x & 63;
  const size_t r = (size_t)blockIdx.x * 4 + w;
  const bf16* yr = Y + r * CH;

  short8 a = *(const short8*)(yr + 8 * l);
  short4v b4 = *(const short4v*)(yr + 512 + 4 * l);
  float v[12];
#pragma unroll
  for (int j = 0; j < 8; j++) v[j] = bf2f(a[j]);
#pragma unroll
  for (int j = 0; j < 4; j++) v[8 + j] = bf2f(b4[j]);

  float s1 = 0.f, s2 = 0.f;
#pragma unroll
  for (int j = 0; j < 12; j++) { s1 += v[j]; s2 += v[j] * v[j]; }
#pragma unroll
  for (int m = 1; m <= 32; m <<= 1) {
    s1 += __shfl_xor(s1, m, 64);
    s2 += __shfl_xor(s2, m, 64);
  }
  float mu = s1 * (1.0f / 768.0f);
  float var = s2 * (1.0f / 768.0f) - mu * mu;
  float rs = rsqrtf(var + 1e-5f);

  float4 g0 = *(const float4*)(g + 8 * l);
  float4 g1 = *(const float4*)(g + 8 * l + 4);
  float4 g2 = *(const float4*)(g + 512 + 4 * l);
  float4 b0 = *(const float4*)(be + 8 * l);
  float4 b1 = *(const float4*)(be + 8 * l + 4);
  float4 b2 = *(const float4*)(be + 512 + 4 * l);

  float4 o0, o1, o2;
  o0.x = (v[0] - mu) * rs * g0.x + b0.x;
  o0.y = (v[1] - mu) * rs * g0.y + b0.y;
  o0.z = (v[2] - mu) * rs * g0.z + b0.z;
  o0.w = (v[3] - mu) * rs * g0.w + b0.w;
  o1.x = (v[4] - mu) * rs * g1.x + b1.x;
  o1.y = (v[5] - mu) * rs * g1.y + b1.y;
  o1.z = (v[6] - mu) * rs * g1.z + b1.z;
  o1.w = (v[7] - mu) * rs * g1.w + b1.w;
  o2.x = (v[8] - mu) * rs * g2.x + b2.x;
  o2.y = (v[9] - mu) * rs * g2.y + b2.y;
  o2.z = (v[10] - mu) * rs * g2.z + b2.z;
  o2.w = (v[11] - mu) * rs * g2.w + b2.w;

  float* orow = out + r * CH;
  *(float4*)(orow + 8 * l) = o0;
  *(float4*)(orow + 8 * l + 4) = o1;
  *(float4*)(orow + 512 + 4 * l) = o2;
}

// ---------------- launch ----------------
extern "C" void kernel_launch(void* const* d_in, const int* in_sizes, int n_in,
                              void* d_out, int out_size, void* d_ws, size_t ws_size,
                              hipStream_t stream) {
  (void)in_sizes; (void)n_in; (void)out_size; (void)ws_size;
  const float* x     = (const float*)d_in[0];
  const float* smask = (const float*)d_in[1];
  const float* wqkv  = (const float*)d_in[2];
  const float* bqkv  = (const float*)d_in[3];
  const float* wproj = (const float*)d_in[4];
  const float* bproj = (const float*)d_in[5];
  const float* table = (const float*)d_in[6];
  const float* lng   = (const float*)d_in[7];
  const float* lnb   = (const float*)d_in[8];
  const int*   rpi   = (const int*)d_in[9];
  float* out = (float*)d_out;

  char* ws = (char*)d_ws;
  bf16*  xb   = (bf16*)(ws);                      // 77,070,336 B (live for proj residual)
  bf16*  wqb  = (bf16*)(ws + 77070336);           //  3,538,944 B
  bf16*  wpb  = (bf16*)(ws + 80609280);           //  1,179,648 B
  bf16*  comb = (bf16*)(ws + 81788928);           // 12,582,912 B
  bf16*  qkvT = (bf16*)(ws + 94371840);           // 231,211,008 B
  bf16*  aout = (bf16*)(ws + 325582848);          // 77,070,336 B (head-plane [h][M][32])
  bf16*  yb   = (bf16*)(ws + 94371840);           // aliases qkvT (dead after attn)

  cvt_bf16<<<37632, 256, 0, stream>>>(x, xb, 9633792);
  cvt_bf16<<<1728, 256, 0, stream>>>(wqkv, wqb, 442368);
  cvt_bf16<<<576, 256, 0, stream>>>(wproj, wpb, 147456);
  build_comb<<<6144, 256, 0, stream>>>(table, rpi, smask, comb);
  qkv_gemm<<<1764, 512, 131072, stream>>>(xb, wqb, bqkv, qkvT);
  attn_kernel<<<dim3(1024, 6), 256, 0, stream>>>(qkvT, comb, aout);
  proj_gemm<<<2352, 256, 0, stream>>>(aout, wpb, bproj, xb, yb);
  ln_kernel<<<12544, 256, 0, stream>>>(yb, lng, lnb, out);
}

// Round 19
// 500.506 us; speedup vs baseline: 1.0710x; 1.0125x over previous
//
#include <hip/hip_runtime.h>
#include <hip/hip_bf16.h>

#define SEQ 49
#define CH 768
#define NH 24
#define HD 32
#define NB 1024
#define NWIN 64
#define MTOT (NB*SEQ)      // 50176

typedef __hip_bfloat16 bf16;
typedef __attribute__((ext_vector_type(8))) short short8;
typedef __attribute__((ext_vector_type(4))) short short4v;
typedef __attribute__((ext_vector_type(4))) float f32x4;

#define MD  ((size_t)MTOT * HD)     // elems per head plane: 1,605,632
#define NHMD ((size_t)NH * MD)      // elems per q/k/v section

__device__ __forceinline__ void gload16(const void* g, void* l) {
  __builtin_amdgcn_global_load_lds((__attribute__((address_space(1))) void*)g,
                                   (__attribute__((address_space(3))) void*)l,
                                   16, 0, 0);
}

__device__ __forceinline__ float bf2f(short s) {
  return __uint_as_float(((unsigned int)(unsigned short)s) << 16);
}

__device__ __forceinline__ void cvt4(const float* in, bf16* o, int i) {
  float4 v = ((const float4*)in)[i];
  union { bf16 b[4]; short4 s; } u;
  u.b[0] = __float2bfloat16(v.x);
  u.b[1] = __float2bfloat16(v.y);
  u.b[2] = __float2bfloat16(v.z);
  u.b[3] = __float2bfloat16(v.w);
  ((short4*)o)[i] = u.s;
}

// ---------------- fused prologue: cvt_x | cvt_wqkv | cvt_wproj | build_comb ----------------
// grid 46080 x 256: [0,37632) x->xb; [37632,39360) wqkv; [39360,39936) wproj;
// [39936,46080) comb (fragment-ordered bf16, pre-scaled by log2e; pads -1e30).
__global__ __launch_bounds__(256) void prep_kernel(
    const float* __restrict__ x, const float* __restrict__ wqkv,
    const float* __restrict__ wproj, const float* __restrict__ table,
    const int* __restrict__ rpi, const float* __restrict__ smask,
    bf16* __restrict__ xb, bf16* __restrict__ wqb, bf16* __restrict__ wpb,
    bf16* __restrict__ comb)
{
  const int bid = blockIdx.x;
  const int tid = threadIdx.x;
  if (bid < 37632) {
    cvt4(x, xb, bid * 256 + tid);
  } else if (bid < 39360) {
    cvt4(wqkv, wqb, (bid - 37632) * 256 + tid);
  } else if (bid < 39936) {
    cvt4(wproj, wpb, (bid - 39360) * 256 + tid);
  } else {
    int i = (bid - 39936) * 256 + tid;        // < 64*24*1024
    int idx = i * 4;
    int e0 = idx & 7;
    int l = (idx >> 3) & 63;
    int jj = (idx >> 9) & 7;
    int sh = idx >> 12;
    int h = sh % NH;
    int s = sh / NH;
    union { bf16 b[4]; short4 v; } u;
#pragma unroll
    for (int k = 0; k < 4; k++) {
      int j = jj * 8 + e0 + k;
      int mt = j >> 4, nt = (j >> 2) & 3, r = j & 3;
      int m = 16 * mt + 4 * (l >> 4) + r;
      int n = 16 * nt + (l & 15);
      float v = -1e30f;
      if (m < SEQ && n < SEQ)
        v = (table[rpi[m * SEQ + n] * NH + h] + smask[s * SEQ * SEQ + m * SEQ + n])
            * 1.4426950408889634f;
      u.b[k] = __float2bfloat16(v);
    }
    *(short4*)(comb + idx) = u.v;
  }
}

// ---------------- kernel 1: QKV GEMM, 256x256 tile, BK=64 ----------------
// 4 phases/K-tile, counted vmcnt (T4): issue order B0B1|B2B3|A0A2|A1A3,
// entry waits p0:vmcnt(2), p2:vmcnt(4) (last tile: 0). Loads span barriers.
__global__ __launch_bounds__(512) void qkv_gemm(
    const bf16* __restrict__ A, const bf16* __restrict__ Bw,
    const float* __restrict__ bias, bf16* __restrict__ C)
{
  extern __shared__ __align__(16) bf16 lds[];  // [A0|A1|B0|B1] x 16384 elems
  const int tid = threadIdx.x;
  const int w = tid >> 6, l = tid & 63;
  const int lr = l & 15, lg = l >> 4;
  const int wm = w >> 2, wn = w & 3;

  const int flat = blockIdx.x;
  const int xcd = flat & 7, lid = flat >> 3;
  const int wgid = (xcd < 4 ? xcd * 221 : 884 + (xcd - 4) * 220) + lid;
  const int bm = wgid / 9, bn = wgid - 9 * bm;

  const bf16* gA[4];
  const bf16* gB[4];
  int ldst[4];
#pragma unroll
  for (int j = 0; j < 4; j++) {
    int c = j * 512 + tid;
    int row = c >> 3, cpos = c & 7;
    int srcch = cpos ^ (row & 7);
    gA[j] = A + ((size_t)(bm * 256 + row)) * CH + srcch * 8;
    gB[j] = Bw + ((size_t)(bn * 256 + row)) * CH + srcch * 8;
    ldst[j] = c * 8;
  }

  f32x4 acc[8][4];
  f32x4 zero4 = {0.f, 0.f, 0.f, 0.f};
#pragma unroll
  for (int i = 0; i < 8; i++)
#pragma unroll
    for (int j = 0; j < 4; j++) acc[i][j] = zero4;

  int offA[8][2], offB[4][2];
#pragma unroll
  for (int mi = 0; mi < 8; mi++)
#pragma unroll
    for (int ks = 0; ks < 2; ks++) {
      int rowa = wm * 128 + mi * 16 + lr;
      offA[mi][ks] = rowa * 64 + ((lg + 4 * ks) ^ (rowa & 7)) * 8;
    }
#pragma unroll
  for (int nj = 0; nj < 4; nj++)
#pragma unroll
    for (int ks = 0; ks < 2; ks++) {
      int rowb = wn * 64 + nj * 16 + lr;
      offB[nj][ks] = rowb * 64 + ((lg + 4 * ks) ^ (rowb & 7)) * 8;
    }

  // prologue: tile 0 -> buf0, issue order B0,B1,B2,B3,A0,A2,A1,A3
  gload16(gB[0], lds + 32768 + ldst[0]);
  gload16(gB[1], lds + 32768 + ldst[1]);
  gload16(gB[2], lds + 32768 + ldst[2]);
  gload16(gB[3], lds + 32768 + ldst[3]);
  gload16(gA[0], lds + ldst[0]);
  gload16(gA[2], lds + ldst[2]);
  gload16(gA[1], lds + ldst[1]);
  gload16(gA[3], lds + ldst[3]);

  for (int t = 0; t < 12; ++t) {
    const int cur = t & 1;
    const bf16* cA = lds + cur * 16384;
    const bf16* cB = lds + 32768 + cur * 16384;
    bf16* nA = lds + (cur ^ 1) * 16384;
    bf16* nB = lds + 32768 + (cur ^ 1) * 16384;
    const int kk = (t + 1) * 64;
    const bool pf = (t < 11);
#pragma unroll
    for (int p = 0; p < 4; ++p) {
      const int hp = p >> 1, ks = p & 1;
      if (p == 0) {
        asm volatile("s_waitcnt vmcnt(2)" ::: "memory");   // A0,A2,B* of tile t landed
      } else if (p == 2) {
        if (pf) asm volatile("s_waitcnt vmcnt(4)" ::: "memory");  // A1,A3 of tile t landed
        else    asm volatile("s_waitcnt vmcnt(0)" ::: "memory");
      }
      __builtin_amdgcn_sched_barrier(0);
      __builtin_amdgcn_s_barrier();          // propagate per-wave completion CU-wide
      __builtin_amdgcn_sched_barrier(0);
      short8 af[4], bfv[4];
#pragma unroll
      for (int mi = 0; mi < 4; mi++) af[mi] = *(const short8*)(cA + offA[hp * 4 + mi][ks]);
#pragma unroll
      for (int nj = 0; nj < 4; nj++) bfv[nj] = *(const short8*)(cB + offB[nj][ks]);
      if (pf) {
        if (p == 0) { gload16(gB[0] + kk, nB + ldst[0]); gload16(gB[1] + kk, nB + ldst[1]); }
        if (p == 1) { gload16(gB[2] + kk, nB + ldst[2]); gload16(gB[3] + kk, nB + ldst[3]); }
        if (p == 2) { gload16(gA[0] + kk, nA + ldst[0]); gload16(gA[2] + kk, nA + ldst[2]); }
        if (p == 3) { gload16(gA[1] + kk, nA + ldst[1]); gload16(gA[3] + kk, nA + ldst[3]); }
      }
      asm volatile("s_waitcnt lgkmcnt(0)" ::: "memory");
      __builtin_amdgcn_sched_barrier(0);
      __builtin_amdgcn_s_setprio(1);
#pragma unroll
      for (int mi = 0; mi < 4; mi++)
#pragma unroll
        for (int nj = 0; nj < 4; nj++)
          acc[hp * 4 + mi][nj] =
              __builtin_amdgcn_mfma_f32_16x16x32_bf16(af[mi], bfv[nj], acc[hp * 4 + mi][nj], 0, 0, 0);
      __builtin_amdgcn_s_setprio(0);
    }
  }

  const float scale = 0.25503487724583985f;  // log2(e)/sqrt(32)
  const int colbase = bn * 256 + 64 * wn;
  const int rowbase = bm * 256 + 128 * wm;
#pragma unroll
  for (int nj = 0; nj < 4; nj++) {
    const int cb16 = colbase + 16 * nj;
    const int sec = cb16 / 768;              // 0=q 1=k 2=v
    const int rem = cb16 - sec * 768;
    const int h = rem >> 5;
    const int dbase = rem & 31;              // 0 or 16
    float bv = bias[cb16 + lr];
    if (sec == 2) {
      const size_t vbase = 2 * NHMD + ((size_t)h * HD + dbase + lr) * MTOT;
#pragma unroll
      for (int mi = 0; mi < 8; mi++) {
        size_t row = rowbase + 16 * mi + 4 * lg;
        union { bf16 b[4]; short4 s; } u;
#pragma unroll
        for (int r = 0; r < 4; r++) u.b[r] = __float2bfloat16(acc[mi][nj][r] + bv);
        *(short4*)(C + vbase + row) = u.s;
      }
    } else {
      const float mul = (sec == 0) ? scale : 1.0f;
      const size_t base = (size_t)sec * NHMD + (size_t)h * MD + dbase + lr;
#pragma unroll
      for (int mi = 0; mi < 8; mi++) {
#pragma unroll
        for (int r = 0; r < 4; r++) {
          size_t row = rowbase + 16 * mi + 4 * lg + r;
          C[base + row * HD] = __float2bfloat16((acc[mi][nj][r] + bv) * mul);
        }
      }
    }
  }
}

// ---------------- kernel 2: attention (per-mt phased, 4 waves/SIMD) ----------------
// aout head-plane layout [h][M][32]: each (wave,mt) writes dense 1 KB.
__global__ __launch_bounds__(256, 4) void attn_kernel(
    const bf16* __restrict__ qkvT, const bf16* __restrict__ comb,
    bf16* __restrict__ aoutP)
{
  __shared__ __align__(16) bf16 P[4][64 * 72];
  const int tid = threadIdx.x;
  const int w = tid >> 6, l = tid & 63;
  const int lr = l & 15, lg = l >> 4;
  const int b = blockIdx.x;
  const int h = blockIdx.y * 4 + w;
  const size_t rowb = (size_t)b * SEQ;
  f32x4 zero4 = {0.f, 0.f, 0.f, 0.f};

  const bf16* qb = qkvT + (size_t)h * MD + rowb * HD;          // q pre-scaled (log2e/sqrt32)
  const bf16* kb = qkvT + NHMD + (size_t)h * MD + rowb * HD;
  const bf16* vT = qkvT + 2 * NHMD + (size_t)h * HD * MTOT;    // [32][M]
  bf16* ao = aoutP + (size_t)h * MD + rowb * HD;               // [h][M][32] plane

  short8 kf[4];
#pragma unroll
  for (int nt = 0; nt < 4; nt++)
    kf[nt] = *(const short8*)(kb + (16 * nt + lr) * HD + 8 * lg);

  short8 pb[2][2];
#pragma unroll
  for (int kt = 0; kt < 2; kt++)
#pragma unroll
    for (int dt = 0; dt < 2; dt++)
      pb[kt][dt] = *(const short8*)(vT + ((size_t)(16 * dt + lr)) * MTOT + rowb + 32 * kt + 8 * lg);

  const bf16* cbp = comb + (((size_t)(b & (NWIN - 1)) * NH + h) << 12);
  float inv[4][4];

#pragma unroll
  for (int mt = 0; mt < 4; mt++) {
    short8 qf = *(const short8*)(qb + (16 * mt + lr) * HD + 8 * lg);
    f32x4 s4[4];
#pragma unroll
    for (int nt = 0; nt < 4; nt++)
      s4[nt] = __builtin_amdgcn_mfma_f32_16x16x32_bf16(qf, kf[nt], zero4, 0, 0, 0);
    short8 c0 = *(const short8*)(cbp + ((2 * mt) * 64 + l) * 8);
    short8 c1 = *(const short8*)(cbp + ((2 * mt + 1) * 64 + l) * 8);
#pragma unroll
    for (int e = 0; e < 8; e++) s4[e >> 2][e & 3] += bf2f(c0[e]);
#pragma unroll
    for (int e = 0; e < 8; e++) s4[2 + (e >> 2)][e & 3] += bf2f(c1[e]);
#pragma unroll
    for (int r = 0; r < 4; r++) {
      float t = 0.f;
#pragma unroll
      for (int nt = 0; nt < 4; nt++) {
        float e = exp2f(s4[nt][r]);
        s4[nt][r] = e;
        t += e;
      }
      t += __shfl_xor(t, 1, 64);
      t += __shfl_xor(t, 2, 64);
      t += __shfl_xor(t, 4, 64);
      t += __shfl_xor(t, 8, 64);
      inv[mt][r] = 1.0f / t;
    }
#pragma unroll
    for (int nt = 0; nt < 4; nt++)
#pragma unroll
      for (int r = 0; r < 4; r++)
        P[w][(16 * mt + 4 * lg + r) * 72 + 16 * nt + lr] = __float2bfloat16(s4[nt][r]);
  }

  f32x4 o[4][2];
#pragma unroll
  for (int mt = 0; mt < 4; mt++) { o[mt][0] = zero4; o[mt][1] = zero4; }
#pragma unroll
  for (int kt = 0; kt < 2; kt++) {
    short8 pa[4];
#pragma unroll
    for (int mt = 0; mt < 4; mt++)
      pa[mt] = *(const short8*)(&P[w][(16 * mt + lr) * 72 + 32 * kt + 8 * lg]);
#pragma unroll
    for (int mt = 0; mt < 4; mt++)
#pragma unroll
      for (int dt = 0; dt < 2; dt++)
        o[mt][dt] = __builtin_amdgcn_mfma_f32_16x16x32_bf16(pa[mt], pb[kt][dt], o[mt][dt], 0, 0, 0);
  }

#pragma unroll
  for (int mt = 0; mt < 4; mt++)
#pragma unroll
    for (int dt = 0; dt < 2; dt++)
#pragma unroll
      for (int r = 0; r < 4; r++) {
        int m = 16 * mt + 4 * lg + r;
        if (m < SEQ)
          ao[(size_t)m * HD + 16 * dt + lr] =
              __float2bfloat16(o[mt][dt][r] * inv[mt][r]);
      }
}

// ---------------- kernel 3: proj GEMM + bias + residual(bf16), 2-phase ----------------
// A operand read from head-plane layout [h][M][32]; K-tile advance = 2*MD elems.
__global__ __launch_bounds__(256) void proj_gemm(
    const bf16* __restrict__ Ap, const bf16* __restrict__ Bw,
    const float* __restrict__ bias, const bf16* __restrict__ xb,
    bf16* __restrict__ Y)
{
  __shared__ __align__(16) bf16 As[2 * 128 * 64];
  __shared__ __align__(16) bf16 Bs[2 * 128 * 64];
  const int tid = threadIdx.x;
  const int w = tid >> 6, l = tid & 63;
  const int lr = l & 15, lg = l >> 4;
  const int wm = w >> 1, wn = w & 1;

  const int flat = blockIdx.x;                 // 2352 = 8 x 294
  const int wg = (flat & 7) * 294 + (flat >> 3);
  const int bm = wg / 6, bn = wg - 6 * (wg / 6);

  const bf16* gA[4];
  const bf16* gB[4];
  int ldst[4];
#pragma unroll
  for (int j = 0; j < 4; j++) {
    int c = j * 256 + tid;
    int row = c >> 3, cpos = c & 7;
    int srcch = cpos ^ (row & 7);
    int col0 = srcch * 8;                      // 0..63 within first 2 head planes
    gA[j] = Ap + (size_t)(col0 >> 5) * MD + ((size_t)(bm * 128 + row)) * HD + (col0 & 31);
    gB[j] = Bw + ((size_t)(bn * 128 + row)) * CH + srcch * 8;
    ldst[j] = c * 8;
  }

  f32x4 acc[4][4];
  f32x4 zero4 = {0.f, 0.f, 0.f, 0.f};
#pragma unroll
  for (int i = 0; i < 4; i++)
#pragma unroll
    for (int j = 0; j < 4; j++) acc[i][j] = zero4;

  int offA[4][2], offB[4][2];
#pragma unroll
  for (int mi = 0; mi < 4; mi++) {
#pragma unroll
    for (int ks = 0; ks < 2; ks++) {
      int rowa = 64 * wm + 16 * mi + lr;
      offA[mi][ks] = rowa * 64 + ((lg + 4 * ks) ^ (rowa & 7)) * 8;
      int rowb = 64 * wn + 16 * mi + lr;
      offB[mi][ks] = rowb * 64 + ((lg + 4 * ks) ^ (rowb & 7)) * 8;
    }
  }

#pragma unroll
  for (int j = 0; j < 4; j++) gload16(gA[j], As + ldst[j]);
#pragma unroll
  for (int j = 0; j < 4; j++) gload16(gB[j], Bs + ldst[j]);

  for (int t = 0; t < 12; ++t) {
    const int base = (t & 1) * 8192;
    asm volatile("s_waitcnt vmcnt(0)" ::: "memory");
    __builtin_amdgcn_sched_barrier(0);
    __builtin_amdgcn_s_barrier();
    __builtin_amdgcn_sched_barrier(0);
    const bf16* cA = As + base;
    const bf16* cB = Bs + base;
    bf16* nA = As + (base ^ 8192);
    bf16* nB = Bs + (base ^ 8192);
    const int kk = (t + 1) * 64;               // B advance (row-major)
    const size_t ka = (size_t)(t + 1) * 2 * MD; // A advance (2 head planes/tile)
    const bool pf = (t < 11);
#pragma unroll
    for (int ks = 0; ks < 2; ks++) {
      short8 af[4], bfv[4];
#pragma unroll
      for (int mi = 0; mi < 4; mi++) {
        af[mi] = *(const short8*)(cA + offA[mi][ks]);
        bfv[mi] = *(const short8*)(cB + offB[mi][ks]);
      }
      if (pf && ks == 0) {
#pragma unroll
        for (int j = 0; j < 4; j++) {
          gload16(gA[j] + ka, nA + ldst[j]);
          gload16(gB[j] + kk, nB + ldst[j]);
        }
      }
      asm volatile("s_waitcnt lgkmcnt(0)" ::: "memory");
      __builtin_amdgcn_sched_barrier(0);
      __builtin_amdgcn_s_setprio(1);
#pragma unroll
      for (int mi = 0; mi < 4; mi++)
#pragma unroll
        for (int nj = 0; nj < 4; nj++)
          acc[mi][nj] = __builtin_amdgcn_mfma_f32_16x16x32_bf16(af[mi], bfv[nj], acc[mi][nj], 0, 0, 0);
      __builtin_amdgcn_s_setprio(0);
    }
  }

  const int colbase = bn * 128 + 64 * wn;
  const int rowbase = bm * 128 + 64 * wm;
#pragma unroll
  for (int nj = 0; nj < 4; nj++) {
    int col = colbase + 16 * nj + lr;
    float bv = bias[col];
#pragma unroll
    for (int mi = 0; mi < 4; mi++) {
#pragma unroll
      for (int r = 0; r < 4; r++) {
        size_t row = rowbase + 16 * mi + 4 * lg + r;
        float v = acc[mi][nj][r] + bv + bf2f(((const short*)xb)[row * CH + col]);
        Y[row * CH + col] = __float2bfloat16(v);
      }
    }
  }
}

// ---------------- kernel 4: LayerNorm ----------------
__global__ __launch_bounds__(256) void ln_kernel(
    const bf16* __restrict__ Y, const float* __restrict__ g,
    const float* __restrict__ be, float* __restrict__ out)
{
  const int w = threadIdx.x >> 6, l = threadIdx.x & 63;
  const size_t r = (size_t)blockIdx.x * 4 + w;
  const bf16* yr = Y + r * CH;

  short8 a = *(const short8*)(yr + 8 * l);
  short4v b4 = *(const short4v*)(yr + 512 + 4 * l);
  float v[12];
#pragma unroll
  for (int j = 0; j < 8; j++) v[j] = bf2f(a[j]);
#pragma unroll
  for (int j = 0; j < 4; j++) v[8 + j] = bf2f(b4[j]);

  float s1 = 0.f, s2 = 0.f;
#pragma unroll
  for (int j = 0; j < 12; j++) { s1 += v[j]; s2 += v[j] * v[j]; }
#pragma unroll
  for (int m = 1; m <= 32; m <<= 1) {
    s1 += __shfl_xor(s1, m, 64);
    s2 += __shfl_xor(s2, m, 64);
  }
  float mu = s1 * (1.0f / 768.0f);
  float var = s2 * (1.0f / 768.0f) - mu * mu;
  float rs = rsqrtf(var + 1e-5f);

  float4 g0 = *(const float4*)(g + 8 * l);
  float4 g1 = *(const float4*)(g + 8 * l + 4);
  float4 g2 = *(const float4*)(g + 512 + 4 * l);
  float4 b0 = *(const float4*)(be + 8 * l);
  float4 b1 = *(const float4*)(be + 8 * l + 4);
  float4 b2 = *(const float4*)(be + 512 + 4 * l);

  float4 o0, o1, o2;
  o0.x = (v[0] - mu) * rs * g0.x + b0.x;
  o0.y = (v[1] - mu) * rs * g0.y + b0.y;
  o0.z = (v[2] - mu) * rs * g0.z + b0.z;
  o0.w = (v[3] - mu) * rs * g0.w + b0.w;
  o1.x = (v[4] - mu) * rs * g1.x + b1.x;
  o1.y = (v[5] - mu) * rs * g1.y + b1.y;
  o1.z = (v[6] - mu) * rs * g1.z + b1.z;
  o1.w = (v[7] - mu) * rs * g1.w + b1.w;
  o2.x = (v[8] - mu) * rs * g2.x + b2.x;
  o2.y = (v[9] - mu) * rs * g2.y + b2.y;
  o2.z = (v[10] - mu) * rs * g2.z + b2.z;
  o2.w = (v[11] - mu) * rs * g2.w + b2.w;

  float* orow = out + r * CH;
  *(float4*)(orow + 8 * l) = o0;
  *(float4*)(orow + 8 * l + 4) = o1;
  *(float4*)(orow + 512 + 4 * l) = o2;
}

// ---------------- launch ----------------
extern "C" void kernel_launch(void* const* d_in, const int* in_sizes, int n_in,
                              void* d_out, int out_size, void* d_ws, size_t ws_size,
                              hipStream_t stream) {
  (void)in_sizes; (void)n_in; (void)out_size; (void)ws_size;
  const float* x     = (const float*)d_in[0];
  const float* smask = (const float*)d_in[1];
  const float* wqkv  = (const float*)d_in[2];
  const float* bqkv  = (const float*)d_in[3];
  const float* wproj = (const float*)d_in[4];
  const float* bproj = (const float*)d_in[5];
  const float* table = (const float*)d_in[6];
  const float* lng   = (const float*)d_in[7];
  const float* lnb   = (const float*)d_in[8];
  const int*   rpi   = (const int*)d_in[9];
  float* out = (float*)d_out;

  char* ws = (char*)d_ws;
  bf16*  xb   = (bf16*)(ws);                      // 77,070,336 B (live for proj residual)
  bf16*  wqb  = (bf16*)(ws + 77070336);           //  3,538,944 B
  bf16*  wpb  = (bf16*)(ws + 80609280);           //  1,179,648 B
  bf16*  comb = (bf16*)(ws + 81788928);           // 12,582,912 B
  bf16*  qkvT = (bf16*)(ws + 94371840);           // 231,211,008 B
  bf16*  aout = (bf16*)(ws + 325582848);          // 77,070,336 B (head-plane [h][M][32])
  bf16*  yb   = (bf16*)(ws + 94371840);           // aliases qkvT (dead after attn)

  prep_kernel<<<46080, 256, 0, stream>>>(x, wqkv, wproj, table, rpi, smask,
                                         xb, wqb, wpb, comb);
  qkv_gemm<<<1764, 512, 131072, stream>>>(xb, wqb, bqkv, qkvT);
  attn_kernel<<<dim3(1024, 6), 256, 0, stream>>>(qkvT, comb, aout);
  proj_gemm<<<2352, 256, 0, stream>>>(aout, wpb, bproj, xb, yb);
  ln_kernel<<<12544, 256, 0, stream>>>(yb, lng, lnb, out);
}

// Round 20
// 499.058 us; speedup vs baseline: 1.0741x; 1.0029x over previous
//
#include <hip/hip_runtime.h>
#include <hip/hip_bf16.h>

#define SEQ 49
#define CH 768
#define NH 24
#define HD 32
#define NB 1024
#define NWIN 64
#define MTOT (NB*SEQ)      // 50176

typedef __hip_bfloat16 bf16;
typedef __attribute__((ext_vector_type(8))) short short8;
typedef __attribute__((ext_vector_type(4))) short short4v;
typedef __attribute__((ext_vector_type(4))) float f32x4;

#define MD  ((size_t)MTOT * HD)     // elems per head plane: 1,605,632
#define NHMD ((size_t)NH * MD)      // elems per q/k/v section

__device__ __forceinline__ void gload16(const void* g, void* l) {
  __builtin_amdgcn_global_load_lds((__attribute__((address_space(1))) void*)g,
                                   (__attribute__((address_space(3))) void*)l,
                                   16, 0, 0);
}

__device__ __forceinline__ float bf2f(short s) {
  return __uint_as_float(((unsigned int)(unsigned short)s) << 16);
}

__device__ __forceinline__ void cvt4(const float* in, bf16* o, int i) {
  float4 v = ((const float4*)in)[i];
  union { bf16 b[4]; short4 s; } u;
  u.b[0] = __float2bfloat16(v.x);
  u.b[1] = __float2bfloat16(v.y);
  u.b[2] = __float2bfloat16(v.z);
  u.b[3] = __float2bfloat16(v.w);
  ((short4*)o)[i] = u.s;
}

// ---------------- fused prologue: cvt_x | cvt_wqkv | cvt_wproj | build_comb ----------------
__global__ __launch_bounds__(256) void prep_kernel(
    const float* __restrict__ x, const float* __restrict__ wqkv,
    const float* __restrict__ wproj, const float* __restrict__ table,
    const int* __restrict__ rpi, const float* __restrict__ smask,
    bf16* __restrict__ xb, bf16* __restrict__ wqb, bf16* __restrict__ wpb,
    bf16* __restrict__ comb)
{
  const int bid = blockIdx.x;
  const int tid = threadIdx.x;
  if (bid < 37632) {
    cvt4(x, xb, bid * 256 + tid);
  } else if (bid < 39360) {
    cvt4(wqkv, wqb, (bid - 37632) * 256 + tid);
  } else if (bid < 39936) {
    cvt4(wproj, wpb, (bid - 39360) * 256 + tid);
  } else {
    int i = (bid - 39936) * 256 + tid;        // < 64*24*1024
    int idx = i * 4;
    int e0 = idx & 7;
    int l = (idx >> 3) & 63;
    int jj = (idx >> 9) & 7;
    int sh = idx >> 12;
    int h = sh % NH;
    int s = sh / NH;
    union { bf16 b[4]; short4 v; } u;
#pragma unroll
    for (int k = 0; k < 4; k++) {
      int j = jj * 8 + e0 + k;
      int mt = j >> 4, nt = (j >> 2) & 3, r = j & 3;
      int m = 16 * mt + 4 * (l >> 4) + r;
      int n = 16 * nt + (l & 15);
      float v = -1e30f;
      if (m < SEQ && n < SEQ)
        v = (table[rpi[m * SEQ + n] * NH + h] + smask[s * SEQ * SEQ + m * SEQ + n])
            * 1.4426950408889634f;
      u.b[k] = __float2bfloat16(v);
    }
    *(short4*)(comb + idx) = u.v;
  }
}

// ---------------- kernel 1: QKV GEMM, 256x256 tile, BK=64 ----------------
// 4 phases/K-tile, counted vmcnt (T4): issue order B0B1|B2B3|A0A2|A1A3,
// entry waits p0:vmcnt(2), p2:vmcnt(4) (last tile: 0). Loads span barriers.
__global__ __launch_bounds__(512) void qkv_gemm(
    const bf16* __restrict__ A, const bf16* __restrict__ Bw,
    const float* __restrict__ bias, bf16* __restrict__ C)
{
  extern __shared__ __align__(16) bf16 lds[];  // [A0|A1|B0|B1] x 16384 elems
  const int tid = threadIdx.x;
  const int w = tid >> 6, l = tid & 63;
  const int lr = l & 15, lg = l >> 4;
  const int wm = w >> 2, wn = w & 3;

  const int flat = blockIdx.x;
  const int xcd = flat & 7, lid = flat >> 3;
  const int wgid = (xcd < 4 ? xcd * 221 : 884 + (xcd - 4) * 220) + lid;
  const int bm = wgid / 9, bn = wgid - 9 * bm;

  const bf16* gA[4];
  const bf16* gB[4];
  int ldst[4];
#pragma unroll
  for (int j = 0; j < 4; j++) {
    int c = j * 512 + tid;
    int row = c >> 3, cpos = c & 7;
    int srcch = cpos ^ (row & 7);
    gA[j] = A + ((size_t)(bm * 256 + row)) * CH + srcch * 8;
    gB[j] = Bw + ((size_t)(bn * 256 + row)) * CH + srcch * 8;
    ldst[j] = c * 8;
  }

  f32x4 acc[8][4];
  f32x4 zero4 = {0.f, 0.f, 0.f, 0.f};
#pragma unroll
  for (int i = 0; i < 8; i++)
#pragma unroll
    for (int j = 0; j < 4; j++) acc[i][j] = zero4;

  int offA[8][2], offB[4][2];
#pragma unroll
  for (int mi = 0; mi < 8; mi++)
#pragma unroll
    for (int ks = 0; ks < 2; ks++) {
      int rowa = wm * 128 + mi * 16 + lr;
      offA[mi][ks] = rowa * 64 + ((lg + 4 * ks) ^ (rowa & 7)) * 8;
    }
#pragma unroll
  for (int nj = 0; nj < 4; nj++)
#pragma unroll
    for (int ks = 0; ks < 2; ks++) {
      int rowb = wn * 64 + nj * 16 + lr;
      offB[nj][ks] = rowb * 64 + ((lg + 4 * ks) ^ (rowb & 7)) * 8;
    }

  // prologue: tile 0 -> buf0, issue order B0,B1,B2,B3,A0,A2,A1,A3
  gload16(gB[0], lds + 32768 + ldst[0]);
  gload16(gB[1], lds + 32768 + ldst[1]);
  gload16(gB[2], lds + 32768 + ldst[2]);
  gload16(gB[3], lds + 32768 + ldst[3]);
  gload16(gA[0], lds + ldst[0]);
  gload16(gA[2], lds + ldst[2]);
  gload16(gA[1], lds + ldst[1]);
  gload16(gA[3], lds + ldst[3]);

  for (int t = 0; t < 12; ++t) {
    const int cur = t & 1;
    const bf16* cA = lds + cur * 16384;
    const bf16* cB = lds + 32768 + cur * 16384;
    bf16* nA = lds + (cur ^ 1) * 16384;
    bf16* nB = lds + 32768 + (cur ^ 1) * 16384;
    const int kk = (t + 1) * 64;
    const bool pf = (t < 11);
#pragma unroll
    for (int p = 0; p < 4; ++p) {
      const int hp = p >> 1, ks = p & 1;
      if (p == 0) {
        asm volatile("s_waitcnt vmcnt(2)" ::: "memory");   // A0,A2,B* of tile t landed
      } else if (p == 2) {
        if (pf) asm volatile("s_waitcnt vmcnt(4)" ::: "memory");  // A1,A3 of tile t landed
        else    asm volatile("s_waitcnt vmcnt(0)" ::: "memory");
      }
      __builtin_amdgcn_sched_barrier(0);
      __builtin_amdgcn_s_barrier();          // propagate per-wave completion CU-wide
      __builtin_amdgcn_sched_barrier(0);
      short8 af[4], bfv[4];
#pragma unroll
      for (int mi = 0; mi < 4; mi++) af[mi] = *(const short8*)(cA + offA[hp * 4 + mi][ks]);
#pragma unroll
      for (int nj = 0; nj < 4; nj++) bfv[nj] = *(const short8*)(cB + offB[nj][ks]);
      if (pf) {
        if (p == 0) { gload16(gB[0] + kk, nB + ldst[0]); gload16(gB[1] + kk, nB + ldst[1]); }
        if (p == 1) { gload16(gB[2] + kk, nB + ldst[2]); gload16(gB[3] + kk, nB + ldst[3]); }
        if (p == 2) { gload16(gA[0] + kk, nA + ldst[0]); gload16(gA[2] + kk, nA + ldst[2]); }
        if (p == 3) { gload16(gA[1] + kk, nA + ldst[1]); gload16(gA[3] + kk, nA + ldst[3]); }
      }
      asm volatile("s_waitcnt lgkmcnt(0)" ::: "memory");
      __builtin_amdgcn_sched_barrier(0);
      __builtin_amdgcn_s_setprio(1);
#pragma unroll
      for (int mi = 0; mi < 4; mi++)
#pragma unroll
        for (int nj = 0; nj < 4; nj++)
          acc[hp * 4 + mi][nj] =
              __builtin_amdgcn_mfma_f32_16x16x32_bf16(af[mi], bfv[nj], acc[hp * 4 + mi][nj], 0, 0, 0);
      __builtin_amdgcn_s_setprio(0);
    }
  }

  const float scale = 0.25503487724583985f;  // log2(e)/sqrt(32)
  const int colbase = bn * 256 + 64 * wn;
  const int rowbase = bm * 256 + 128 * wm;
#pragma unroll
  for (int nj = 0; nj < 4; nj++) {
    const int cb16 = colbase + 16 * nj;
    const int sec = cb16 / 768;              // 0=q 1=k 2=v
    const int rem = cb16 - sec * 768;
    const int h = rem >> 5;
    const int dbase = rem & 31;              // 0 or 16
    float bv = bias[cb16 + lr];
    if (sec == 2) {
      const size_t vbase = 2 * NHMD + ((size_t)h * HD + dbase + lr) * MTOT;
#pragma unroll
      for (int mi = 0; mi < 8; mi++) {
        size_t row = rowbase + 16 * mi + 4 * lg;
        union { bf16 b[4]; short4 s; } u;
#pragma unroll
        for (int r = 0; r < 4; r++) u.b[r] = __float2bfloat16(acc[mi][nj][r] + bv);
        *(short4*)(C + vbase + row) = u.s;
      }
    } else {
      const float mul = (sec == 0) ? scale : 1.0f;
      const size_t base = (size_t)sec * NHMD + (size_t)h * MD + dbase + lr;
#pragma unroll
      for (int mi = 0; mi < 8; mi++) {
#pragma unroll
        for (int r = 0; r < 4; r++) {
          size_t row = rowbase + 16 * mi + 4 * lg + r;
          C[base + row * HD] = __float2bfloat16((acc[mi][nj][r] + bv) * mul);
        }
      }
    }
  }
}

// ---------------- kernel 2: attention (hoisted q loads + per-mt phased softmax) ----------------
// All 20 VMEM loads issued up front; softmax per-mt keeps transient state small.
__global__ __launch_bounds__(256, 4) void attn_kernel(
    const bf16* __restrict__ qkvT, const bf16* __restrict__ comb,
    bf16* __restrict__ aoutP)
{
  __shared__ __align__(16) bf16 P[4][64 * 72];
  const int tid = threadIdx.x;
  const int w = tid >> 6, l = tid & 63;
  const int lr = l & 15, lg = l >> 4;
  const int b = blockIdx.x;
  const int h = blockIdx.y * 4 + w;
  const size_t rowb = (size_t)b * SEQ;
  f32x4 zero4 = {0.f, 0.f, 0.f, 0.f};

  const bf16* qb = qkvT + (size_t)h * MD + rowb * HD;          // q pre-scaled (log2e/sqrt32)
  const bf16* kb = qkvT + NHMD + (size_t)h * MD + rowb * HD;
  const bf16* vT = qkvT + 2 * NHMD + (size_t)h * HD * MTOT;    // [32][M]
  bf16* ao = aoutP + (size_t)h * MD + rowb * HD;               // [h][M][32] plane

  short8 qf[4], kf[4];
#pragma unroll
  for (int mt = 0; mt < 4; mt++)
    qf[mt] = *(const short8*)(qb + (16 * mt + lr) * HD + 8 * lg);
#pragma unroll
  for (int nt = 0; nt < 4; nt++)
    kf[nt] = *(const short8*)(kb + (16 * nt + lr) * HD + 8 * lg);

  short8 pb[2][2];
#pragma unroll
  for (int kt = 0; kt < 2; kt++)
#pragma unroll
    for (int dt = 0; dt < 2; dt++)
      pb[kt][dt] = *(const short8*)(vT + ((size_t)(16 * dt + lr)) * MTOT + rowb + 32 * kt + 8 * lg);

  const bf16* cbp = comb + (((size_t)(b & (NWIN - 1)) * NH + h) << 12);
  float inv[4][4];

#pragma unroll
  for (int mt = 0; mt < 4; mt++) {
    f32x4 s4[4];
#pragma unroll
    for (int nt = 0; nt < 4; nt++)
      s4[nt] = __builtin_amdgcn_mfma_f32_16x16x32_bf16(qf[mt], kf[nt], zero4, 0, 0, 0);
    short8 c0 = *(const short8*)(cbp + ((2 * mt) * 64 + l) * 8);
    short8 c1 = *(const short8*)(cbp + ((2 * mt + 1) * 64 + l) * 8);
#pragma unroll
    for (int e = 0; e < 8; e++) s4[e >> 2][e & 3] += bf2f(c0[e]);
#pragma unroll
    for (int e = 0; e < 8; e++) s4[2 + (e >> 2)][e & 3] += bf2f(c1[e]);
#pragma unroll
    for (int r = 0; r < 4; r++) {
      float t = 0.f;
#pragma unroll
      for (int nt = 0; nt < 4; nt++) {
        float e = exp2f(s4[nt][r]);
        s4[nt][r] = e;
        t += e;
      }
      t += __shfl_xor(t, 1, 64);
      t += __shfl_xor(t, 2, 64);
      t += __shfl_xor(t, 4, 64);
      t += __shfl_xor(t, 8, 64);
      inv[mt][r] = 1.0f / t;
    }
#pragma unroll
    for (int nt = 0; nt < 4; nt++)
#pragma unroll
      for (int r = 0; r < 4; r++)
        P[w][(16 * mt + 4 * lg + r) * 72 + 16 * nt + lr] = __float2bfloat16(s4[nt][r]);
  }

  f32x4 o[4][2];
#pragma unroll
  for (int mt = 0; mt < 4; mt++) { o[mt][0] = zero4; o[mt][1] = zero4; }
#pragma unroll
  for (int kt = 0; kt < 2; kt++) {
    short8 pa[4];
#pragma unroll
    for (int mt = 0; mt < 4; mt++)
      pa[mt] = *(const short8*)(&P[w][(16 * mt + lr) * 72 + 32 * kt + 8 * lg]);
#pragma unroll
    for (int mt = 0; mt < 4; mt++)
#pragma unroll
      for (int dt = 0; dt < 2; dt++)
        o[mt][dt] = __builtin_amdgcn_mfma_f32_16x16x32_bf16(pa[mt], pb[kt][dt], o[mt][dt], 0, 0, 0);
  }

#pragma unroll
  for (int mt = 0; mt < 4; mt++)
#pragma unroll
    for (int dt = 0; dt < 2; dt++)
#pragma unroll
      for (int r = 0; r < 4; r++) {
        int m = 16 * mt + 4 * lg + r;
        if (m < SEQ)
          ao[(size_t)m * HD + 16 * dt + lr] =
              __float2bfloat16(o[mt][dt][r] * inv[mt][r]);
      }
}

// ---------------- kernel 3: proj GEMM + bias + residual(bf16), 2-phase ----------------
// A operand read from head-plane layout [h][M][32]; K-tile advance = 2*MD elems.
__global__ __launch_bounds__(256) void proj_gemm(
    const bf16* __restrict__ Ap, const bf16* __restrict__ Bw,
    const float* __restrict__ bias, const bf16* __restrict__ xb,
    bf16* __restrict__ Y)
{
  __shared__ __align__(16) bf16 As[2 * 128 * 64];
  __shared__ __align__(16) bf16 Bs[2 * 128 * 64];
  const int tid = threadIdx.x;
  const int w = tid >> 6, l = tid & 63;
  const int lr = l & 15, lg = l >> 4;
  const int wm = w >> 1, wn = w & 1;

  const int flat = blockIdx.x;                 // 2352 = 8 x 294
  const int wg = (flat & 7) * 294 + (flat >> 3);
  const int bm = wg / 6, bn = wg - 6 * (wg / 6);

  const bf16* gA[4];
  const bf16* gB[4];
  int ldst[4];
#pragma unroll
  for (int j = 0; j < 4; j++) {
    int c = j * 256 + tid;
    int row = c >> 3, cpos = c & 7;
    int srcch = cpos ^ (row & 7);
    int col0 = srcch * 8;                      // 0..63 within first 2 head planes
    gA[j] = Ap + (size_t)(col0 >> 5) * MD + ((size_t)(bm * 128 + row)) * HD + (col0 & 31);
    gB[j] = Bw + ((size_t)(bn * 128 + row)) * CH + srcch * 8;
    ldst[j] = c * 8;
  }

  f32x4 acc[4][4];
  f32x4 zero4 = {0.f, 0.f, 0.f, 0.f};
#pragma unroll
  for (int i = 0; i < 4; i++)
#pragma unroll
    for (int j = 0; j < 4; j++) acc[i][j] = zero4;

  int offA[4][2], offB[4][2];
#pragma unroll
  for (int mi = 0; mi < 4; mi++) {
#pragma unroll
    for (int ks = 0; ks < 2; ks++) {
      int rowa = 64 * wm + 16 * mi + lr;
      offA[mi][ks] = rowa * 64 + ((lg + 4 * ks) ^ (rowa & 7)) * 8;
      int rowb = 64 * wn + 16 * mi + lr;
      offB[mi][ks] = rowb * 64 + ((lg + 4 * ks) ^ (rowb & 7)) * 8;
    }
  }

#pragma unroll
  for (int j = 0; j < 4; j++) gload16(gA[j], As + ldst[j]);
#pragma unroll
  for (int j = 0; j < 4; j++) gload16(gB[j], Bs + ldst[j]);

  for (int t = 0; t < 12; ++t) {
    const int base = (t & 1) * 8192;
    asm volatile("s_waitcnt vmcnt(0)" ::: "memory");
    __builtin_amdgcn_sched_barrier(0);
    __builtin_amdgcn_s_barrier();
    __builtin_amdgcn_sched_barrier(0);
    const bf16* cA = As + base;
    const bf16* cB = Bs + base;
    bf16* nA = As + (base ^ 8192);
    bf16* nB = Bs + (base ^ 8192);
    const int kk = (t + 1) * 64;               // B advance (row-major)
    const size_t ka = (size_t)(t + 1) * 2 * MD; // A advance (2 head planes/tile)
    const bool pf = (t < 11);
#pragma unroll
    for (int ks = 0; ks < 2; ks++) {
      short8 af[4], bfv[4];
#pragma unroll
      for (int mi = 0; mi < 4; mi++) {
        af[mi] = *(const short8*)(cA + offA[mi][ks]);
        bfv[mi] = *(const short8*)(cB + offB[mi][ks]);
      }
      if (pf && ks == 0) {
#pragma unroll
        for (int j = 0; j < 4; j++) {
          gload16(gA[j] + ka, nA + ldst[j]);
          gload16(gB[j] + kk, nB + ldst[j]);
        }
      }
      asm volatile("s_waitcnt lgkmcnt(0)" ::: "memory");
      __builtin_amdgcn_sched_barrier(0);
      __builtin_amdgcn_s_setprio(1);
#pragma unroll
      for (int mi = 0; mi < 4; mi++)
#pragma unroll
        for (int nj = 0; nj < 4; nj++)
          acc[mi][nj] = __builtin_amdgcn_mfma_f32_16x16x32_bf16(af[mi], bfv[nj], acc[mi][nj], 0, 0, 0);
      __builtin_amdgcn_s_setprio(0);
    }
  }

  const int colbase = bn * 128 + 64 * wn;
  const int rowbase = bm * 128 + 64 * wm;
#pragma unroll
  for (int nj = 0; nj < 4; nj++) {
    int col = colbase + 16 * nj + lr;
    float bv = bias[col];
#pragma unroll
    for (int mi = 0; mi < 4; mi++) {
#pragma unroll
      for (int r = 0; r < 4; r++) {
        size_t row = rowbase + 16 * mi + 4 * lg + r;
        float v = acc[mi][nj][r] + bv + bf2f(((const short*)xb)[row * CH + col]);
        Y[row * CH + col] = __float2bfloat16(v);
      }
    }
  }
}

// ---------------- kernel 4: LayerNorm ----------------
__global__ __launch_bounds__(256) void ln_kernel(
    const bf16* __restrict__ Y, const float* __restrict__ g,
    const float* __restrict__ be, float* __restrict__ out)
{
  const int w = threadIdx.x >> 6, l = threadIdx.x & 63;
  const size_t r = (size_t)blockIdx.x * 4 + w;
  const bf16* yr = Y + r * CH;

  short8 a = *(const short8*)(yr + 8 * l);
  short4v b4 = *(const short4v*)(yr + 512 + 4 * l);
  float v[12];
#pragma unroll
  for (int j = 0; j < 8; j++) v[j] = bf2f(a[j]);
#pragma unroll
  for (int j = 0; j < 4; j++) v[8 + j] = bf2f(b4[j]);

  float s1 = 0.f, s2 = 0.f;
#pragma unroll
  for (int j = 0; j < 12; j++) { s1 += v[j]; s2 += v[j] * v[j]; }
#pragma unroll
  for (int m = 1; m <= 32; m <<= 1) {
    s1 += __shfl_xor(s1, m, 64);
    s2 += __shfl_xor(s2, m, 64);
  }
  float mu = s1 * (1.0f / 768.0f);
  float var = s2 * (1.0f / 768.0f) - mu * mu;
  float rs = rsqrtf(var + 1e-5f);

  float4 g0 = *(const float4*)(g + 8 * l);
  float4 g1 = *(const float4*)(g + 8 * l + 4);
  float4 g2 = *(const float4*)(g + 512 + 4 * l);
  float4 b0 = *(const float4*)(be + 8 * l);
  float4 b1 = *(const float4*)(be + 8 * l + 4);
  float4 b2 = *(const float4*)(be + 512 + 4 * l);

  float4 o0, o1, o2;
  o0.x = (v[0] - mu) * rs * g0.x + b0.x;
  o0.y = (v[1] - mu) * rs * g0.y + b0.y;
  o0.z = (v[2] - mu) * rs * g0.z + b0.z;
  o0.w = (v[3] - mu) * rs * g0.w + b0.w;
  o1.x = (v[4] - mu) * rs * g1.x + b1.x;
  o1.y = (v[5] - mu) * rs * g1.y + b1.y;
  o1.z = (v[6] - mu) * rs * g1.z + b1.z;
  o1.w = (v[7] - mu) * rs * g1.w + b1.w;
  o2.x = (v[8] - mu) * rs * g2.x + b2.x;
  o2.y = (v[9] - mu) * rs * g2.y + b2.y;
  o2.z = (v[10] - mu) * rs * g2.z + b2.z;
  o2.w = (v[11] - mu) * rs * g2.w + b2.w;

  float* orow = out + r * CH;
  *(float4*)(orow + 8 * l) = o0;
  *(float4*)(orow + 8 * l + 4) = o1;
  *(float4*)(orow + 512 + 4 * l) = o2;
}

// ---------------- launch ----------------
extern "C" void kernel_launch(void* const* d_in, const int* in_sizes, int n_in,
                              void* d_out, int out_size, void* d_ws, size_t ws_size,
                              hipStream_t stream) {
  (void)in_sizes; (void)n_in; (void)out_size; (void)ws_size;
  const float* x     = (const float*)d_in[0];
  const float* smask = (const float*)d_in[1];
  const float* wqkv  = (const float*)d_in[2];
  const float* bqkv  = (const float*)d_in[3];
  const float* wproj = (const float*)d_in[4];
  const float* bproj = (const float*)d_in[5];
  const float* table = (const float*)d_in[6];
  const float* lng   = (const float*)d_in[7];
  const float* lnb   = (const float*)d_in[8];
  const int*   rpi   = (const int*)d_in[9];
  float* out = (float*)d_out;

  char* ws = (char*)d_ws;
  bf16*  xb   = (bf16*)(ws);                      // 77,070,336 B (live for proj residual)
  bf16*  wqb  = (bf16*)(ws + 77070336);           //  3,538,944 B
  bf16*  wpb  = (bf16*)(ws + 80609280);           //  1,179,648 B
  bf16*  comb = (bf16*)(ws + 81788928);           // 12,582,912 B
  bf16*  qkvT = (bf16*)(ws + 94371840);           // 231,211,008 B
  bf16*  aout = (bf16*)(ws + 325582848);          // 77,070,336 B (head-plane [h][M][32])
  bf16*  yb   = (bf16*)(ws + 94371840);           // aliases qkvT (dead after attn)

  prep_kernel<<<46080, 256, 0, stream>>>(x, wqkv, wproj, table, rpi, smask,
                                         xb, wqb, wpb, comb);
  qkv_gemm<<<1764, 512, 131072, stream>>>(xb, wqb, bqkv, qkvT);
  attn_kernel<<<dim3(1024, 6), 256, 0, stream>>>(qkvT, comb, aout);
  proj_gemm<<<2352, 256, 0, stream>>>(aout, wpb, bproj, xb, yb);
  ln_kernel<<<12544, 256, 0, stream>>>(yb, lng, lnb, out);
}

// Round 21
// 495.910 us; speedup vs baseline: 1.0809x; 1.0063x over previous
//
#include <hip/hip_runtime.h>
#include <hip/hip_bf16.h>

#define SEQ 49
#define CH 768
#define NH 24
#define HD 32
#define NB 1024
#define NWIN 64
#define MTOT (NB*SEQ)      // 50176

typedef __hip_bfloat16 bf16;
typedef __attribute__((ext_vector_type(8))) short short8;
typedef __attribute__((ext_vector_type(4))) short short4v;
typedef __attribute__((ext_vector_type(4))) float f32x4;

#define MD  ((size_t)MTOT * HD)     // elems per head plane: 1,605,632
#define NHMD ((size_t)NH * MD)      // elems per q/k/v section

__device__ __forceinline__ void gload16(const void* g, void* l) {
  __builtin_amdgcn_global_load_lds((__attribute__((address_space(1))) void*)g,
                                   (__attribute__((address_space(3))) void*)l,
                                   16, 0, 0);
}

__device__ __forceinline__ float bf2f(short s) {
  return __uint_as_float(((unsigned int)(unsigned short)s) << 16);
}

__device__ __forceinline__ void cvt4(const float* in, bf16* o, int i) {
  float4 v = ((const float4*)in)[i];
  union { bf16 b[4]; short4 s; } u;
  u.b[0] = __float2bfloat16(v.x);
  u.b[1] = __float2bfloat16(v.y);
  u.b[2] = __float2bfloat16(v.z);
  u.b[3] = __float2bfloat16(v.w);
  ((short4*)o)[i] = u.s;
}

// ---------------- fused prologue: cvt_x | cvt_wqkv | cvt_wproj | build_comb ----------------
__global__ __launch_bounds__(256) void prep_kernel(
    const float* __restrict__ x, const float* __restrict__ wqkv,
    const float* __restrict__ wproj, const float* __restrict__ table,
    const int* __restrict__ rpi, const float* __restrict__ smask,
    bf16* __restrict__ xb, bf16* __restrict__ wqb, bf16* __restrict__ wpb,
    bf16* __restrict__ comb)
{
  const int bid = blockIdx.x;
  const int tid = threadIdx.x;
  if (bid < 37632) {
    cvt4(x, xb, bid * 256 + tid);
  } else if (bid < 39360) {
    cvt4(wqkv, wqb, (bid - 37632) * 256 + tid);
  } else if (bid < 39936) {
    cvt4(wproj, wpb, (bid - 39360) * 256 + tid);
  } else {
    int i = (bid - 39936) * 256 + tid;        // < 64*24*1024
    int idx = i * 4;
    int e0 = idx & 7;
    int l = (idx >> 3) & 63;
    int jj = (idx >> 9) & 7;
    int sh = idx >> 12;
    int h = sh % NH;
    int s = sh / NH;
    union { bf16 b[4]; short4 v; } u;
#pragma unroll
    for (int k = 0; k < 4; k++) {
      int j = jj * 8 + e0 + k;
      int mt = j >> 4, nt = (j >> 2) & 3, r = j & 3;
      int m = 16 * mt + 4 * (l >> 4) + r;
      int n = 16 * nt + (l & 15);
      float v = -1e30f;
      if (m < SEQ && n < SEQ)
        v = (table[rpi[m * SEQ + n] * NH + h] + smask[s * SEQ * SEQ + m * SEQ + n])
            * 1.4426950408889634f;
      u.b[k] = __float2bfloat16(v);
    }
    *(short4*)(comb + idx) = u.v;
  }
}

// ---------------- kernel 1: QKV GEMM, 256x256 tile, BK=64 ----------------
// 4 phases/K-tile, counted vmcnt (T4); barriers ONLY at p0 (reuse hazard +
// vmcnt(2) propagate) and p2 (vmcnt(4) propagate) -- p1/p3 barriers removed.
__global__ __launch_bounds__(512) void qkv_gemm(
    const bf16* __restrict__ A, const bf16* __restrict__ Bw,
    const float* __restrict__ bias, bf16* __restrict__ C)
{
  extern __shared__ __align__(16) bf16 lds[];  // [A0|A1|B0|B1] x 16384 elems
  const int tid = threadIdx.x;
  const int w = tid >> 6, l = tid & 63;
  const int lr = l & 15, lg = l >> 4;
  const int wm = w >> 2, wn = w & 3;

  const int flat = blockIdx.x;
  const int xcd = flat & 7, lid = flat >> 3;
  const int wgid = (xcd < 4 ? xcd * 221 : 884 + (xcd - 4) * 220) + lid;
  const int bm = wgid / 9, bn = wgid - 9 * bm;

  const bf16* gA[4];
  const bf16* gB[4];
  int ldst[4];
#pragma unroll
  for (int j = 0; j < 4; j++) {
    int c = j * 512 + tid;
    int row = c >> 3, cpos = c & 7;
    int srcch = cpos ^ (row & 7);
    gA[j] = A + ((size_t)(bm * 256 + row)) * CH + srcch * 8;
    gB[j] = Bw + ((size_t)(bn * 256 + row)) * CH + srcch * 8;
    ldst[j] = c * 8;
  }

  f32x4 acc[8][4];
  f32x4 zero4 = {0.f, 0.f, 0.f, 0.f};
#pragma unroll
  for (int i = 0; i < 8; i++)
#pragma unroll
    for (int j = 0; j < 4; j++) acc[i][j] = zero4;

  int offA[8][2], offB[4][2];
#pragma unroll
  for (int mi = 0; mi < 8; mi++)
#pragma unroll
    for (int ks = 0; ks < 2; ks++) {
      int rowa = wm * 128 + mi * 16 + lr;
      offA[mi][ks] = rowa * 64 + ((lg + 4 * ks) ^ (rowa & 7)) * 8;
    }
#pragma unroll
  for (int nj = 0; nj < 4; nj++)
#pragma unroll
    for (int ks = 0; ks < 2; ks++) {
      int rowb = wn * 64 + nj * 16 + lr;
      offB[nj][ks] = rowb * 64 + ((lg + 4 * ks) ^ (rowb & 7)) * 8;
    }

  // prologue: tile 0 -> buf0, issue order B0,B1,B2,B3,A0,A2,A1,A3
  gload16(gB[0], lds + 32768 + ldst[0]);
  gload16(gB[1], lds + 32768 + ldst[1]);
  gload16(gB[2], lds + 32768 + ldst[2]);
  gload16(gB[3], lds + 32768 + ldst[3]);
  gload16(gA[0], lds + ldst[0]);
  gload16(gA[2], lds + ldst[2]);
  gload16(gA[1], lds + ldst[1]);
  gload16(gA[3], lds + ldst[3]);

  for (int t = 0; t < 12; ++t) {
    const int cur = t & 1;
    const bf16* cA = lds + cur * 16384;
    const bf16* cB = lds + 32768 + cur * 16384;
    bf16* nA = lds + (cur ^ 1) * 16384;
    bf16* nB = lds + 32768 + (cur ^ 1) * 16384;
    const int kk = (t + 1) * 64;
    const bool pf = (t < 11);
#pragma unroll
    for (int p = 0; p < 4; ++p) {
      const int hp = p >> 1, ks = p & 1;
      if (p == 0) {
        asm volatile("s_waitcnt vmcnt(2)" ::: "memory");   // A0,A2,B* of tile t landed
        __builtin_amdgcn_sched_barrier(0);
        __builtin_amdgcn_s_barrier();        // + all waves done reading buf^1 (tile t-1)
        __builtin_amdgcn_sched_barrier(0);
      } else if (p == 2) {
        if (pf) asm volatile("s_waitcnt vmcnt(4)" ::: "memory");  // A1,A3 of tile t landed
        else    asm volatile("s_waitcnt vmcnt(0)" ::: "memory");
        __builtin_amdgcn_sched_barrier(0);
        __builtin_amdgcn_s_barrier();
        __builtin_amdgcn_sched_barrier(0);
      }
      short8 af[4], bfv[4];
#pragma unroll
      for (int mi = 0; mi < 4; mi++) af[mi] = *(const short8*)(cA + offA[hp * 4 + mi][ks]);
#pragma unroll
      for (int nj = 0; nj < 4; nj++) bfv[nj] = *(const short8*)(cB + offB[nj][ks]);
      if (pf) {
        if (p == 0) { gload16(gB[0] + kk, nB + ldst[0]); gload16(gB[1] + kk, nB + ldst[1]); }
        if (p == 1) { gload16(gB[2] + kk, nB + ldst[2]); gload16(gB[3] + kk, nB + ldst[3]); }
        if (p == 2) { gload16(gA[0] + kk, nA + ldst[0]); gload16(gA[2] + kk, nA + ldst[2]); }
        if (p == 3) { gload16(gA[1] + kk, nA + ldst[1]); gload16(gA[3] + kk, nA + ldst[3]); }
      }
      asm volatile("s_waitcnt lgkmcnt(0)" ::: "memory");
      __builtin_amdgcn_sched_barrier(0);
      __builtin_amdgcn_s_setprio(1);
#pragma unroll
      for (int mi = 0; mi < 4; mi++)
#pragma unroll
        for (int nj = 0; nj < 4; nj++)
          acc[hp * 4 + mi][nj] =
              __builtin_amdgcn_mfma_f32_16x16x32_bf16(af[mi], bfv[nj], acc[hp * 4 + mi][nj], 0, 0, 0);
      __builtin_amdgcn_s_setprio(0);
    }
  }

  const float scale = 0.25503487724583985f;  // log2(e)/sqrt(32)
  const int colbase = bn * 256 + 64 * wn;
  const int rowbase = bm * 256 + 128 * wm;
#pragma unroll
  for (int nj = 0; nj < 4; nj++) {
    const int cb16 = colbase + 16 * nj;
    const int sec = cb16 / 768;              // 0=q 1=k 2=v
    const int rem = cb16 - sec * 768;
    const int h = rem >> 5;
    const int dbase = rem & 31;              // 0 or 16
    float bv = bias[cb16 + lr];
    if (sec == 2) {
      const size_t vbase = 2 * NHMD + ((size_t)h * HD + dbase + lr) * MTOT;
#pragma unroll
      for (int mi = 0; mi < 8; mi++) {
        size_t row = rowbase + 16 * mi + 4 * lg;
        union { bf16 b[4]; short4 s; } u;
#pragma unroll
        for (int r = 0; r < 4; r++) u.b[r] = __float2bfloat16(acc[mi][nj][r] + bv);
        *(short4*)(C + vbase + row) = u.s;
      }
    } else {
      const float mul = (sec == 0) ? scale : 1.0f;
      const size_t base = (size_t)sec * NHMD + (size_t)h * MD + dbase + lr;
#pragma unroll
      for (int mi = 0; mi < 8; mi++) {
#pragma unroll
        for (int r = 0; r < 4; r++) {
          size_t row = rowbase + 16 * mi + 4 * lg + r;
          C[base + row * HD] = __float2bfloat16((acc[mi][nj][r] + bv) * mul);
        }
      }
    }
  }
}

// ---------------- kernel 2: attention (hoisted q loads + per-mt phased softmax) ----------------
__global__ __launch_bounds__(256, 4) void attn_kernel(
    const bf16* __restrict__ qkvT, const bf16* __restrict__ comb,
    bf16* __restrict__ aoutP)
{
  __shared__ __align__(16) bf16 P[4][64 * 72];
  const int tid = threadIdx.x;
  const int w = tid >> 6, l = tid & 63;
  const int lr = l & 15, lg = l >> 4;
  const int b = blockIdx.x;
  const int h = blockIdx.y * 4 + w;
  const size_t rowb = (size_t)b * SEQ;
  f32x4 zero4 = {0.f, 0.f, 0.f, 0.f};

  const bf16* qb = qkvT + (size_t)h * MD + rowb * HD;          // q pre-scaled (log2e/sqrt32)
  const bf16* kb = qkvT + NHMD + (size_t)h * MD + rowb * HD;
  const bf16* vT = qkvT + 2 * NHMD + (size_t)h * HD * MTOT;    // [32][M]
  bf16* ao = aoutP + (size_t)h * MD + rowb * HD;               // [h][M][32] plane

  short8 qf[4], kf[4];
#pragma unroll
  for (int mt = 0; mt < 4; mt++)
    qf[mt] = *(const short8*)(qb + (16 * mt + lr) * HD + 8 * lg);
#pragma unroll
  for (int nt = 0; nt < 4; nt++)
    kf[nt] = *(const short8*)(kb + (16 * nt + lr) * HD + 8 * lg);

  short8 pb[2][2];
#pragma unroll
  for (int kt = 0; kt < 2; kt++)
#pragma unroll
    for (int dt = 0; dt < 2; dt++)
      pb[kt][dt] = *(const short8*)(vT + ((size_t)(16 * dt + lr)) * MTOT + rowb + 32 * kt + 8 * lg);

  const bf16* cbp = comb + (((size_t)(b & (NWIN - 1)) * NH + h) << 12);
  float inv[4][4];

#pragma unroll
  for (int mt = 0; mt < 4; mt++) {
    f32x4 s4[4];
#pragma unroll
    for (int nt = 0; nt < 4; nt++)
      s4[nt] = __builtin_amdgcn_mfma_f32_16x16x32_bf16(qf[mt], kf[nt], zero4, 0, 0, 0);
    short8 c0 = *(const short8*)(cbp + ((2 * mt) * 64 + l) * 8);
    short8 c1 = *(const short8*)(cbp + ((2 * mt + 1) * 64 + l) * 8);
#pragma unroll
    for (int e = 0; e < 8; e++) s4[e >> 2][e & 3] += bf2f(c0[e]);
#pragma unroll
    for (int e = 0; e < 8; e++) s4[2 + (e >> 2)][e & 3] += bf2f(c1[e]);
#pragma unroll
    for (int r = 0; r < 4; r++) {
      float t = 0.f;
#pragma unroll
      for (int nt = 0; nt < 4; nt++) {
        float e = exp2f(s4[nt][r]);
        s4[nt][r] = e;
        t += e;
      }
      t += __shfl_xor(t, 1, 64);
      t += __shfl_xor(t, 2, 64);
      t += __shfl_xor(t, 4, 64);
      t += __shfl_xor(t, 8, 64);
      inv[mt][r] = 1.0f / t;
    }
#pragma unroll
    for (int nt = 0; nt < 4; nt++)
#pragma unroll
      for (int r = 0; r < 4; r++)
        P[w][(16 * mt + 4 * lg + r) * 72 + 16 * nt + lr] = __float2bfloat16(s4[nt][r]);
  }

  f32x4 o[4][2];
#pragma unroll
  for (int mt = 0; mt < 4; mt++) { o[mt][0] = zero4; o[mt][1] = zero4; }
#pragma unroll
  for (int kt = 0; kt < 2; kt++) {
    short8 pa[4];
#pragma unroll
    for (int mt = 0; mt < 4; mt++)
      pa[mt] = *(const short8*)(&P[w][(16 * mt + lr) * 72 + 32 * kt + 8 * lg]);
#pragma unroll
    for (int mt = 0; mt < 4; mt++)
#pragma unroll
      for (int dt = 0; dt < 2; dt++)
        o[mt][dt] = __builtin_amdgcn_mfma_f32_16x16x32_bf16(pa[mt], pb[kt][dt], o[mt][dt], 0, 0, 0);
  }

#pragma unroll
  for (int mt = 0; mt < 4; mt++)
#pragma unroll
    for (int dt = 0; dt < 2; dt++)
#pragma unroll
      for (int r = 0; r < 4; r++) {
        int m = 16 * mt + 4 * lg + r;
        if (m < SEQ)
          ao[(size_t)m * HD + 16 * dt + lr] =
              __float2bfloat16(o[mt][dt][r] * inv[mt][r]);
      }
}

// ---------------- kernel 3: proj GEMM + bias + residual(bf16), 2-phase ----------------
__global__ __launch_bounds__(256) void proj_gemm(
    const bf16* __restrict__ Ap, const bf16* __restrict__ Bw,
    const float* __restrict__ bias, const bf16* __restrict__ xb,
    bf16* __restrict__ Y)
{
  __shared__ __align__(16) bf16 As[2 * 128 * 64];
  __shared__ __align__(16) bf16 Bs[2 * 128 * 64];
  const int tid = threadIdx.x;
  const int w = tid >> 6, l = tid & 63;
  const int lr = l & 15, lg = l >> 4;
  const int wm = w >> 1, wn = w & 1;

  const int flat = blockIdx.x;                 // 2352 = 8 x 294
  const int wg = (flat & 7) * 294 + (flat >> 3);
  const int bm = wg / 6, bn = wg - 6 * (wg / 6);

  const bf16* gA[4];
  const bf16* gB[4];
  int ldst[4];
#pragma unroll
  for (int j = 0; j < 4; j++) {
    int c = j * 256 + tid;
    int row = c >> 3, cpos = c & 7;
    int srcch = cpos ^ (row & 7);
    int col0 = srcch * 8;                      // 0..63 within first 2 head planes
    gA[j] = Ap + (size_t)(col0 >> 5) * MD + ((size_t)(bm * 128 + row)) * HD + (col0 & 31);
    gB[j] = Bw + ((size_t)(bn * 128 + row)) * CH + srcch * 8;
    ldst[j] = c * 8;
  }

  f32x4 acc[4][4];
  f32x4 zero4 = {0.f, 0.f, 0.f, 0.f};
#pragma unroll
  for (int i = 0; i < 4; i++)
#pragma unroll
    for (int j = 0; j < 4; j++) acc[i][j] = zero4;

  int offA[4][2], offB[4][2];
#pragma unroll
  for (int mi = 0; mi < 4; mi++) {
#pragma unroll
    for (int ks = 0; ks < 2; ks++) {
      int rowa = 64 * wm + 16 * mi + lr;
      offA[mi][ks] = rowa * 64 + ((lg + 4 * ks) ^ (rowa & 7)) * 8;
      int rowb = 64 * wn + 16 * mi + lr;
      offB[mi][ks] = rowb * 64 + ((lg + 4 * ks) ^ (rowb & 7)) * 8;
    }
  }

#pragma unroll
  for (int j = 0; j < 4; j++) gload16(gA[j], As + ldst[j]);
#pragma unroll
  for (int j = 0; j < 4; j++) gload16(gB[j], Bs + ldst[j]);

  for (int t = 0; t < 12; ++t) {
    const int base = (t & 1) * 8192;
    asm volatile("s_waitcnt vmcnt(0)" ::: "memory");
    __builtin_amdgcn_sched_barrier(0);
    __builtin_amdgcn_s_barrier();
    __builtin_amdgcn_sched_barrier(0);
    const bf16* cA = As + base;
    const bf16* cB = Bs + base;
    bf16* nA = As + (base ^ 8192);
    bf16* nB = Bs + (base ^ 8192);
    const int kk = (t + 1) * 64;               // B advance (row-major)
    const size_t ka = (size_t)(t + 1) * 2 * MD; // A advance (2 head planes/tile)
    const bool pf = (t < 11);
#pragma unroll
    for (int ks = 0; ks < 2; ks++) {
      short8 af[4], bfv[4];
#pragma unroll
      for (int mi = 0; mi < 4; mi++) {
        af[mi] = *(const short8*)(cA + offA[mi][ks]);
        bfv[mi] = *(const short8*)(cB + offB[mi][ks]);
      }
      if (pf && ks == 0) {
#pragma unroll
        for (int j = 0; j < 4; j++) {
          gload16(gA[j] + ka, nA + ldst[j]);
          gload16(gB[j] + kk, nB + ldst[j]);
        }
      }
      asm volatile("s_waitcnt lgkmcnt(0)" ::: "memory");
      __builtin_amdgcn_sched_barrier(0);
      __builtin_amdgcn_s_setprio(1);
#pragma unroll
      for (int mi = 0; mi < 4; mi++)
#pragma unroll
        for (int nj = 0; nj < 4; nj++)
          acc[mi][nj] = __builtin_amdgcn_mfma_f32_16x16x32_bf16(af[mi], bfv[nj], acc[mi][nj], 0, 0, 0);
      __builtin_amdgcn_s_setprio(0);
    }
  }

  const int colbase = bn * 128 + 64 * wn;
  const int rowbase = bm * 128 + 64 * wm;
#pragma unroll
  for (int nj = 0; nj < 4; nj++) {
    int col = colbase + 16 * nj + lr;
    float bv = bias[col];
#pragma unroll
    for (int mi = 0; mi < 4; mi++) {
#pragma unroll
      for (int r = 0; r < 4; r++) {
        size_t row = rowbase + 16 * mi + 4 * lg + r;
        float v = acc[mi][nj][r] + bv + bf2f(((const short*)xb)[row * CH + col]);
        Y[row * CH + col] = __float2bfloat16(v);
      }
    }
  }
}

// ---------------- kernel 4: LayerNorm ----------------
__global__ __launch_bounds__(256) void ln_kernel(
    const bf16* __restrict__ Y, const float* __restrict__ g,
    const float* __restrict__ be, float* __restrict__ out)
{
  const int w = threadIdx.x >> 6, l = threadIdx.x & 63;
  const size_t r = (size_t)blockIdx.x * 4 + w;
  const bf16* yr = Y + r * CH;

  short8 a = *(const short8*)(yr + 8 * l);
  short4v b4 = *(const short4v*)(yr + 512 + 4 * l);
  float v[12];
#pragma unroll
  for (int j = 0; j < 8; j++) v[j] = bf2f(a[j]);
#pragma unroll
  for (int j = 0; j < 4; j++) v[8 + j] = bf2f(b4[j]);

  float s1 = 0.f, s2 = 0.f;
#pragma unroll
  for (int j = 0; j < 12; j++) { s1 += v[j]; s2 += v[j] * v[j]; }
#pragma unroll
  for (int m = 1; m <= 32; m <<= 1) {
    s1 += __shfl_xor(s1, m, 64);
    s2 += __shfl_xor(s2, m, 64);
  }
  float mu = s1 * (1.0f / 768.0f);
  float var = s2 * (1.0f / 768.0f) - mu * mu;
  float rs = rsqrtf(var + 1e-5f);

  float4 g0 = *(const float4*)(g + 8 * l);
  float4 g1 = *(const float4*)(g + 8 * l + 4);
  float4 g2 = *(const float4*)(g + 512 + 4 * l);
  float4 b0 = *(const float4*)(be + 8 * l);
  float4 b1 = *(const float4*)(be + 8 * l + 4);
  float4 b2 = *(const float4*)(be + 512 + 4 * l);

  float4 o0, o1, o2;
  o0.x = (v[0] - mu) * rs * g0.x + b0.x;
  o0.y = (v[1] - mu) * rs * g0.y + b0.y;
  o0.z = (v[2] - mu) * rs * g0.z + b0.z;
  o0.w = (v[3] - mu) * rs * g0.w + b0.w;
  o1.x = (v[4] - mu) * rs * g1.x + b1.x;
  o1.y = (v[5] - mu) * rs * g1.y + b1.y;
  o1.z = (v[6] - mu) * rs * g1.z + b1.z;
  o1.w = (v[7] - mu) * rs * g1.w + b1.w;
  o2.x = (v[8] - mu) * rs * g2.x + b2.x;
  o2.y = (v[9] - mu) * rs * g2.y + b2.y;
  o2.z = (v[10] - mu) * rs * g2.z + b2.z;
  o2.w = (v[11] - mu) * rs * g2.w + b2.w;

  float* orow = out + r * CH;
  *(float4*)(orow + 8 * l) = o0;
  *(float4*)(orow + 8 * l + 4) = o1;
  *(float4*)(orow + 512 + 4 * l) = o2;
}

// ---------------- launch ----------------
extern "C" void kernel_launch(void* const* d_in, const int* in_sizes, int n_in,
                              void* d_out, int out_size, void* d_ws, size_t ws_size,
                              hipStream_t stream) {
  (void)in_sizes; (void)n_in; (void)out_size; (void)ws_size;
  const float* x     = (const float*)d_in[0];
  const float* smask = (const float*)d_in[1];
  const float* wqkv  = (const float*)d_in[2];
  const float* bqkv  = (const float*)d_in[3];
  const float* wproj = (const float*)d_in[4];
  const float* bproj = (const float*)d_in[5];
  const float* table = (const float*)d_in[6];
  const float* lng   = (const float*)d_in[7];
  const float* lnb   = (const float*)d_in[8];
  const int*   rpi   = (const int*)d_in[9];
  float* out = (float*)d_out;

  char* ws = (char*)d_ws;
  bf16*  xb   = (bf16*)(ws);                      // 77,070,336 B (live for proj residual)
  bf16*  wqb  = (bf16*)(ws + 77070336);           //  3,538,944 B
  bf16*  wpb  = (bf16*)(ws + 80609280);           //  1,179,648 B
  bf16*  comb = (bf16*)(ws + 81788928);           // 12,582,912 B
  bf16*  qkvT = (bf16*)(ws + 94371840);           // 231,211,008 B
  bf16*  aout = (bf16*)(ws + 325582848);          // 77,070,336 B (head-plane [h][M][32])
  bf16*  yb   = (bf16*)(ws + 94371840);           // aliases qkvT (dead after attn)

  prep_kernel<<<46080, 256, 0, stream>>>(x, wqkv, wproj, table, rpi, smask,
                                         xb, wqb, wpb, comb);
  qkv_gemm<<<1764, 512, 131072, stream>>>(xb, wqb, bqkv, qkvT);
  attn_kernel<<<dim3(1024, 6), 256, 0, stream>>>(qkvT, comb, aout);
  proj_gemm<<<2352, 256, 0, stream>>>(aout, wpb, bproj, xb, yb);
  ln_kernel<<<12544, 256, 0, stream>>>(yb, lng, lnb, out);
}

// Round 22
// 493.776 us; speedup vs baseline: 1.0856x; 1.0043x over previous
//
#include <hip/hip_runtime.h>
#include <hip/hip_bf16.h>

#define SEQ 49
#define CH 768
#define NH 24
#define HD 32
#define NB 1024
#define NWIN 64
#define MTOT (NB*SEQ)      // 50176

typedef __hip_bfloat16 bf16;
typedef __attribute__((ext_vector_type(8))) short short8;
typedef __attribute__((ext_vector_type(4))) short short4v;
typedef __attribute__((ext_vector_type(4))) float f32x4;

#define MD  ((size_t)MTOT * HD)     // elems per head plane: 1,605,632
#define NHMD ((size_t)NH * MD)      // elems per q/k/v section

__device__ __forceinline__ void gload16(const void* g, void* l) {
  __builtin_amdgcn_global_load_lds((__attribute__((address_space(1))) void*)g,
                                   (__attribute__((address_space(3))) void*)l,
                                   16, 0, 0);
}

__device__ __forceinline__ float bf2f(short s) {
  return __uint_as_float(((unsigned int)(unsigned short)s) << 16);
}

__device__ __forceinline__ void cvt4(const float* in, bf16* o, int i) {
  float4 v = ((const float4*)in)[i];
  union { bf16 b[4]; short4 s; } u;
  u.b[0] = __float2bfloat16(v.x);
  u.b[1] = __float2bfloat16(v.y);
  u.b[2] = __float2bfloat16(v.z);
  u.b[3] = __float2bfloat16(v.w);
  ((short4*)o)[i] = u.s;
}

// ---------------- fused prologue: cvt_x | cvt_wqkv | cvt_wproj | build_comb ----------------
__global__ __launch_bounds__(256) void prep_kernel(
    const float* __restrict__ x, const float* __restrict__ wqkv,
    const float* __restrict__ wproj, const float* __restrict__ table,
    const int* __restrict__ rpi, const float* __restrict__ smask,
    bf16* __restrict__ xb, bf16* __restrict__ wqb, bf16* __restrict__ wpb,
    bf16* __restrict__ comb)
{
  const int bid = blockIdx.x;
  const int tid = threadIdx.x;
  if (bid < 37632) {
    cvt4(x, xb, bid * 256 + tid);
  } else if (bid < 39360) {
    cvt4(wqkv, wqb, (bid - 37632) * 256 + tid);
  } else if (bid < 39936) {
    cvt4(wproj, wpb, (bid - 39360) * 256 + tid);
  } else {
    int i = (bid - 39936) * 256 + tid;        // < 64*24*1024
    int idx = i * 4;
    int e0 = idx & 7;
    int l = (idx >> 3) & 63;
    int jj = (idx >> 9) & 7;
    int sh = idx >> 12;
    int h = sh % NH;
    int s = sh / NH;
    union { bf16 b[4]; short4 v; } u;
#pragma unroll
    for (int k = 0; k < 4; k++) {
      int j = jj * 8 + e0 + k;
      int mt = j >> 4, nt = (j >> 2) & 3, r = j & 3;
      int m = 16 * mt + 4 * (l >> 4) + r;
      int n = 16 * nt + (l & 15);
      float v = -1e30f;
      if (m < SEQ && n < SEQ)
        v = (table[rpi[m * SEQ + n] * NH + h] + smask[s * SEQ * SEQ + m * SEQ + n])
            * 1.4426950408889634f;
      u.b[k] = __float2bfloat16(v);
    }
    *(short4*)(comb + idx) = u.v;
  }
}

// ---------------- kernel 1: QKV GEMM, 256x256 tile, BK=64 ----------------
// 4 phases/K-tile, counted vmcnt (T4). Stage issue: p0:{B0,B1} p1:{B2,B3,A0,A2}
// p2:{A1,A3} -> A-loads get 4 phases of latency cover. Entry waits:
// p0:vmcnt(2), p2:vmcnt(6) (last tile: 0). Barriers only at p0 and p2.
__global__ __launch_bounds__(512) void qkv_gemm(
    const bf16* __restrict__ A, const bf16* __restrict__ Bw,
    const float* __restrict__ bias, bf16* __restrict__ C)
{
  extern __shared__ __align__(16) bf16 lds[];  // [A0|A1|B0|B1] x 16384 elems
  const int tid = threadIdx.x;
  const int w = tid >> 6, l = tid & 63;
  const int lr = l & 15, lg = l >> 4;
  const int wm = w >> 2, wn = w & 3;

  const int flat = blockIdx.x;
  const int xcd = flat & 7, lid = flat >> 3;
  const int wgid = (xcd < 4 ? xcd * 221 : 884 + (xcd - 4) * 220) + lid;
  const int bm = wgid / 9, bn = wgid - 9 * bm;

  const bf16* gA[4];
  const bf16* gB[4];
  int ldst[4];
#pragma unroll
  for (int j = 0; j < 4; j++) {
    int c = j * 512 + tid;
    int row = c >> 3, cpos = c & 7;
    int srcch = cpos ^ (row & 7);
    gA[j] = A + ((size_t)(bm * 256 + row)) * CH + srcch * 8;
    gB[j] = Bw + ((size_t)(bn * 256 + row)) * CH + srcch * 8;
    ldst[j] = c * 8;
  }

  f32x4 acc[8][4];
  f32x4 zero4 = {0.f, 0.f, 0.f, 0.f};
#pragma unroll
  for (int i = 0; i < 8; i++)
#pragma unroll
    for (int j = 0; j < 4; j++) acc[i][j] = zero4;

  int offA[8][2], offB[4][2];
#pragma unroll
  for (int mi = 0; mi < 8; mi++)
#pragma unroll
    for (int ks = 0; ks < 2; ks++) {
      int rowa = wm * 128 + mi * 16 + lr;
      offA[mi][ks] = rowa * 64 + ((lg + 4 * ks) ^ (rowa & 7)) * 8;
    }
#pragma unroll
  for (int nj = 0; nj < 4; nj++)
#pragma unroll
    for (int ks = 0; ks < 2; ks++) {
      int rowb = wn * 64 + nj * 16 + lr;
      offB[nj][ks] = rowb * 64 + ((lg + 4 * ks) ^ (rowb & 7)) * 8;
    }

  // prologue: tile 0 -> buf0, issue order B0,B1,B2,B3,A0,A2,A1,A3
  gload16(gB[0], lds + 32768 + ldst[0]);
  gload16(gB[1], lds + 32768 + ldst[1]);
  gload16(gB[2], lds + 32768 + ldst[2]);
  gload16(gB[3], lds + 32768 + ldst[3]);
  gload16(gA[0], lds + ldst[0]);
  gload16(gA[2], lds + ldst[2]);
  gload16(gA[1], lds + ldst[1]);
  gload16(gA[3], lds + ldst[3]);

  for (int t = 0; t < 12; ++t) {
    const int cur = t & 1;
    const bf16* cA = lds + cur * 16384;
    const bf16* cB = lds + 32768 + cur * 16384;
    bf16* nA = lds + (cur ^ 1) * 16384;
    bf16* nB = lds + 32768 + (cur ^ 1) * 16384;
    const int kk = (t + 1) * 64;
    const bool pf = (t < 11);
#pragma unroll
    for (int p = 0; p < 4; ++p) {
      const int hp = p >> 1, ks = p & 1;
      if (p == 0) {
        asm volatile("s_waitcnt vmcnt(2)" ::: "memory");   // B*,A0,A2 of tile t landed
        __builtin_amdgcn_sched_barrier(0);
        __builtin_amdgcn_s_barrier();        // + all waves done reading buf^1 (tile t-1)
        __builtin_amdgcn_sched_barrier(0);
      } else if (p == 2) {
        if (pf) asm volatile("s_waitcnt vmcnt(6)" ::: "memory");  // A1,A3 of tile t landed
        else    asm volatile("s_waitcnt vmcnt(0)" ::: "memory");
        __builtin_amdgcn_sched_barrier(0);
        __builtin_amdgcn_s_barrier();
        __builtin_amdgcn_sched_barrier(0);
      }
      short8 af[4], bfv[4];
#pragma unroll
      for (int mi = 0; mi < 4; mi++) af[mi] = *(const short8*)(cA + offA[hp * 4 + mi][ks]);
#pragma unroll
      for (int nj = 0; nj < 4; nj++) bfv[nj] = *(const short8*)(cB + offB[nj][ks]);
      if (pf) {
        if (p == 0) { gload16(gB[0] + kk, nB + ldst[0]); gload16(gB[1] + kk, nB + ldst[1]); }
        if (p == 1) { gload16(gB[2] + kk, nB + ldst[2]); gload16(gB[3] + kk, nB + ldst[3]);
                      gload16(gA[0] + kk, nA + ldst[0]); gload16(gA[2] + kk, nA + ldst[2]); }
        if (p == 2) { gload16(gA[1] + kk, nA + ldst[1]); gload16(gA[3] + kk, nA + ldst[3]); }
      }
      asm volatile("s_waitcnt lgkmcnt(0)" ::: "memory");
      __builtin_amdgcn_sched_barrier(0);
      __builtin_amdgcn_s_setprio(1);
#pragma unroll
      for (int mi = 0; mi < 4; mi++)
#pragma unroll
        for (int nj = 0; nj < 4; nj++)
          acc[hp * 4 + mi][nj] =
              __builtin_amdgcn_mfma_f32_16x16x32_bf16(af[mi], bfv[nj], acc[hp * 4 + mi][nj], 0, 0, 0);
      __builtin_amdgcn_s_setprio(0);
    }
  }

  const float scale = 0.25503487724583985f;  // log2(e)/sqrt(32)
  const int colbase = bn * 256 + 64 * wn;
  const int rowbase = bm * 256 + 128 * wm;
#pragma unroll
  for (int nj = 0; nj < 4; nj++) {
    const int cb16 = colbase + 16 * nj;
    const int sec = cb16 / 768;              // 0=q 1=k 2=v
    const int rem = cb16 - sec * 768;
    const int h = rem >> 5;
    const int dbase = rem & 31;              // 0 or 16
    float bv = bias[cb16 + lr];
    if (sec == 2) {
      const size_t vbase = 2 * NHMD + ((size_t)h * HD + dbase + lr) * MTOT;
#pragma unroll
      for (int mi = 0; mi < 8; mi++) {
        size_t row = rowbase + 16 * mi + 4 * lg;
        union { bf16 b[4]; short4 s; } u;
#pragma unroll
        for (int r = 0; r < 4; r++) u.b[r] = __float2bfloat16(acc[mi][nj][r] + bv);
        *(short4*)(C + vbase + row) = u.s;
      }
    } else {
      const float mul = (sec == 0) ? scale : 1.0f;
      const size_t base = (size_t)sec * NHMD + (size_t)h * MD + dbase + lr;
#pragma unroll
      for (int mi = 0; mi < 8; mi++) {
#pragma unroll
        for (int r = 0; r < 4; r++) {
          size_t row = rowbase + 16 * mi + 4 * lg + r;
          C[base + row * HD] = __float2bfloat16((acc[mi][nj][r] + bv) * mul);
        }
      }
    }
  }
}

// ---------------- kernel 2: attention (hoisted q loads + per-mt phased softmax) ----------------
__global__ __launch_bounds__(256, 4) void attn_kernel(
    const bf16* __restrict__ qkvT, const bf16* __restrict__ comb,
    bf16* __restrict__ aoutP)
{
  __shared__ __align__(16) bf16 P[4][64 * 72];
  const int tid = threadIdx.x;
  const int w = tid >> 6, l = tid & 63;
  const int lr = l & 15, lg = l >> 4;
  const int b = blockIdx.x;
  const int h = blockIdx.y * 4 + w;
  const size_t rowb = (size_t)b * SEQ;
  f32x4 zero4 = {0.f, 0.f, 0.f, 0.f};

  const bf16* qb = qkvT + (size_t)h * MD + rowb * HD;          // q pre-scaled (log2e/sqrt32)
  const bf16* kb = qkvT + NHMD + (size_t)h * MD + rowb * HD;
  const bf16* vT = qkvT + 2 * NHMD + (size_t)h * HD * MTOT;    // [32][M]
  bf16* ao = aoutP + (size_t)h * MD + rowb * HD;               // [h][M][32] plane

  short8 qf[4], kf[4];
#pragma unroll
  for (int mt = 0; mt < 4; mt++)
    qf[mt] = *(const short8*)(qb + (16 * mt + lr) * HD + 8 * lg);
#pragma unroll
  for (int nt = 0; nt < 4; nt++)
    kf[nt] = *(const short8*)(kb + (16 * nt + lr) * HD + 8 * lg);

  short8 pb[2][2];
#pragma unroll
  for (int kt = 0; kt < 2; kt++)
#pragma unroll
    for (int dt = 0; dt < 2; dt++)
      pb[kt][dt] = *(const short8*)(vT + ((size_t)(16 * dt + lr)) * MTOT + rowb + 32 * kt + 8 * lg);

  const bf16* cbp = comb + (((size_t)(b & (NWIN - 1)) * NH + h) << 12);
  float inv[4][4];

#pragma unroll
  for (int mt = 0; mt < 4; mt++) {
    f32x4 s4[4];
#pragma unroll
    for (int nt = 0; nt < 4; nt++)
      s4[nt] = __builtin_amdgcn_mfma_f32_16x16x32_bf16(qf[mt], kf[nt], zero4, 0, 0, 0);
    short8 c0 = *(const short8*)(cbp + ((2 * mt) * 64 + l) * 8);
    short8 c1 = *(const short8*)(cbp + ((2 * mt + 1) * 64 + l) * 8);
#pragma unroll
    for (int e = 0; e < 8; e++) s4[e >> 2][e & 3] += bf2f(c0[e]);
#pragma unroll
    for (int e = 0; e < 8; e++) s4[2 + (e >> 2)][e & 3] += bf2f(c1[e]);
#pragma unroll
    for (int r = 0; r < 4; r++) {
      float t = 0.f;
#pragma unroll
      for (int nt = 0; nt < 4; nt++) {
        float e = exp2f(s4[nt][r]);
        s4[nt][r] = e;
        t += e;
      }
      t += __shfl_xor(t, 1, 64);
      t += __shfl_xor(t, 2, 64);
      t += __shfl_xor(t, 4, 64);
      t += __shfl_xor(t, 8, 64);
      inv[mt][r] = 1.0f / t;
    }
#pragma unroll
    for (int nt = 0; nt < 4; nt++)
#pragma unroll
      for (int r = 0; r < 4; r++)
        P[w][(16 * mt + 4 * lg + r) * 72 + 16 * nt + lr] = __float2bfloat16(s4[nt][r]);
  }

  f32x4 o[4][2];
#pragma unroll
  for (int mt = 0; mt < 4; mt++) { o[mt][0] = zero4; o[mt][1] = zero4; }
#pragma unroll
  for (int kt = 0; kt < 2; kt++) {
    short8 pa[4];
#pragma unroll
    for (int mt = 0; mt < 4; mt++)
      pa[mt] = *(const short8*)(&P[w][(16 * mt + lr) * 72 + 32 * kt + 8 * lg]);
#pragma unroll
    for (int mt = 0; mt < 4; mt++)
#pragma unroll
      for (int dt = 0; dt < 2; dt++)
        o[mt][dt] = __builtin_amdgcn_mfma_f32_16x16x32_bf16(pa[mt], pb[kt][dt], o[mt][dt], 0, 0, 0);
  }

#pragma unroll
  for (int mt = 0; mt < 4; mt++)
#pragma unroll
    for (int dt = 0; dt < 2; dt++)
#pragma unroll
      for (int r = 0; r < 4; r++) {
        int m = 16 * mt + 4 * lg + r;
        if (m < SEQ)
          ao[(size_t)m * HD + 16 * dt + lr] =
              __float2bfloat16(o[mt][dt][r] * inv[mt][r]);
      }
}

// ---------------- kernel 3: proj GEMM + bias + residual(bf16), 2-phase ----------------
__global__ __launch_bounds__(256) void proj_gemm(
    const bf16* __restrict__ Ap, const bf16* __restrict__ Bw,
    const float* __restrict__ bias, const bf16* __restrict__ xb,
    bf16* __restrict__ Y)
{
  __shared__ __align__(16) bf16 As[2 * 128 * 64];
  __shared__ __align__(16) bf16 Bs[2 * 128 * 64];
  const int tid = threadIdx.x;
  const int w = tid >> 6, l = tid & 63;
  const int lr = l & 15, lg = l >> 4;
  const int wm = w >> 1, wn = w & 1;

  const int flat = blockIdx.x;                 // 2352 = 8 x 294
  const int wg = (flat & 7) * 294 + (flat >> 3);
  const int bm = wg / 6, bn = wg - 6 * (wg / 6);

  const bf16* gA[4];
  const bf16* gB[4];
  int ldst[4];
#pragma unroll
  for (int j = 0; j < 4; j++) {
    int c = j * 256 + tid;
    int row = c >> 3, cpos = c & 7;
    int srcch = cpos ^ (row & 7);
    int col0 = srcch * 8;                      // 0..63 within first 2 head planes
    gA[j] = Ap + (size_t)(col0 >> 5) * MD + ((size_t)(bm * 128 + row)) * HD + (col0 & 31);
    gB[j] = Bw + ((size_t)(bn * 128 + row)) * CH + srcch * 8;
    ldst[j] = c * 8;
  }

  f32x4 acc[4][4];
  f32x4 zero4 = {0.f, 0.f, 0.f, 0.f};
#pragma unroll
  for (int i = 0; i < 4; i++)
#pragma unroll
    for (int j = 0; j < 4; j++) acc[i][j] = zero4;

  int offA[4][2], offB[4][2];
#pragma unroll
  for (int mi = 0; mi < 4; mi++) {
#pragma unroll
    for (int ks = 0; ks < 2; ks++) {
      int rowa = 64 * wm + 16 * mi + lr;
      offA[mi][ks] = rowa * 64 + ((lg + 4 * ks) ^ (rowa & 7)) * 8;
      int rowb = 64 * wn + 16 * mi + lr;
      offB[mi][ks] = rowb * 64 + ((lg + 4 * ks) ^ (rowb & 7)) * 8;
    }
  }

#pragma unroll
  for (int j = 0; j < 4; j++) gload16(gA[j], As + ldst[j]);
#pragma unroll
  for (int j = 0; j < 4; j++) gload16(gB[j], Bs + ldst[j]);

  for (int t = 0; t < 12; ++t) {
    const int base = (t & 1) * 8192;
    asm volatile("s_waitcnt vmcnt(0)" ::: "memory");
    __builtin_amdgcn_sched_barrier(0);
    __builtin_amdgcn_s_barrier();
    __builtin_amdgcn_sched_barrier(0);
    const bf16* cA = As + base;
    const bf16* cB = Bs + base;
    bf16* nA = As + (base ^ 8192);
    bf16* nB = Bs + (base ^ 8192);
    const int kk = (t + 1) * 64;               // B advance (row-major)
    const size_t ka = (size_t)(t + 1) * 2 * MD; // A advance (2 head planes/tile)
    const bool pf = (t < 11);
#pragma unroll
    for (int ks = 0; ks < 2; ks++) {
      short8 af[4], bfv[4];
#pragma unroll
      for (int mi = 0; mi < 4; mi++) {
        af[mi] = *(const short8*)(cA + offA[mi][ks]);
        bfv[mi] = *(const short8*)(cB + offB[mi][ks]);
      }
      if (pf && ks == 0) {
#pragma unroll
        for (int j = 0; j < 4; j++) {
          gload16(gA[j] + ka, nA + ldst[j]);
          gload16(gB[j] + kk, nB + ldst[j]);
        }
      }
      asm volatile("s_waitcnt lgkmcnt(0)" ::: "memory");
      __builtin_amdgcn_sched_barrier(0);
      __builtin_amdgcn_s_setprio(1);
#pragma unroll
      for (int mi = 0; mi < 4; mi++)
#pragma unroll
        for (int nj = 0; nj < 4; nj++)
          acc[mi][nj] = __builtin_amdgcn_mfma_f32_16x16x32_bf16(af[mi], bfv[nj], acc[mi][nj], 0, 0, 0);
      __builtin_amdgcn_s_setprio(0);
    }
  }

  const int colbase = bn * 128 + 64 * wn;
  const int rowbase = bm * 128 + 64 * wm;
#pragma unroll
  for (int nj = 0; nj < 4; nj++) {
    int col = colbase + 16 * nj + lr;
    float bv = bias[col];
#pragma unroll
    for (int mi = 0; mi < 4; mi++) {
#pragma unroll
      for (int r = 0; r < 4; r++) {
        size_t row = rowbase + 16 * mi + 4 * lg + r;
        float v = acc[mi][nj][r] + bv + bf2f(((const short*)xb)[row * CH + col]);
        Y[row * CH + col] = __float2bfloat16(v);
      }
    }
  }
}

// ---------------- kernel 4: LayerNorm ----------------
__global__ __launch_bounds__(256) void ln_kernel(
    const bf16* __restrict__ Y, const float* __restrict__ g,
    const float* __restrict__ be, float* __restrict__ out)
{
  const int w = threadIdx.x >> 6, l = threadIdx.x & 63;
  const size_t r = (size_t)blockIdx.x * 4 + w;
  const bf16* yr = Y + r * CH;

  short8 a = *(const short8*)(yr + 8 * l);
  short4v b4 = *(const short4v*)(yr + 512 + 4 * l);
  float v[12];
#pragma unroll
  for (int j = 0; j < 8; j++) v[j] = bf2f(a[j]);
#pragma unroll
  for (int j = 0; j < 4; j++) v[8 + j] = bf2f(b4[j]);

  float s1 = 0.f, s2 = 0.f;
#pragma unroll
  for (int j = 0; j < 12; j++) { s1 += v[j]; s2 += v[j] * v[j]; }
#pragma unroll
  for (int m = 1; m <= 32; m <<= 1) {
    s1 += __shfl_xor(s1, m, 64);
    s2 += __shfl_xor(s2, m, 64);
  }
  float mu = s1 * (1.0f / 768.0f);
  float var = s2 * (1.0f / 768.0f) - mu * mu;
  float rs = rsqrtf(var + 1e-5f);

  float4 g0 = *(const float4*)(g + 8 * l);
  float4 g1 = *(const float4*)(g + 8 * l + 4);
  float4 g2 = *(const float4*)(g + 512 + 4 * l);
  float4 b0 = *(const float4*)(be + 8 * l);
  float4 b1 = *(const float4*)(be + 8 * l + 4);
  float4 b2 = *(const float4*)(be + 512 + 4 * l);

  float4 o0, o1, o2;
  o0.x = (v[0] - mu) * rs * g0.x + b0.x;
  o0.y = (v[1] - mu) * rs * g0.y + b0.y;
  o0.z = (v[2] - mu) * rs * g0.z + b0.z;
  o0.w = (v[3] - mu) * rs * g0.w + b0.w;
  o1.x = (v[4] - mu) * rs * g1.x + b1.x;
  o1.y = (v[5] - mu) * rs * g1.y + b1.y;
  o1.z = (v[6] - mu) * rs * g1.z + b1.z;
  o1.w = (v[7] - mu) * rs * g1.w + b1.w;
  o2.x = (v[8] - mu) * rs * g2.x + b2.x;
  o2.y = (v[9] - mu) * rs * g2.y + b2.y;
  o2.z = (v[10] - mu) * rs * g2.z + b2.z;
  o2.w = (v[11] - mu) * rs * g2.w + b2.w;

  float* orow = out + r * CH;
  *(float4*)(orow + 8 * l) = o0;
  *(float4*)(orow + 8 * l + 4) = o1;
  *(float4*)(orow + 512 + 4 * l) = o2;
}

// ---------------- launch ----------------
extern "C" void kernel_launch(void* const* d_in, const int* in_sizes, int n_in,
                              void* d_out, int out_size, void* d_ws, size_t ws_size,
                              hipStream_t stream) {
  (void)in_sizes; (void)n_in; (void)out_size; (void)ws_size;
  const float* x     = (const float*)d_in[0];
  const float* smask = (const float*)d_in[1];
  const float* wqkv  = (const float*)d_in[2];
  const float* bqkv  = (const float*)d_in[3];
  const float* wproj = (const float*)d_in[4];
  const float* bproj = (const float*)d_in[5];
  const float* table = (const float*)d_in[6];
  const float* lng   = (const float*)d_in[7];
  const float* lnb   = (const float*)d_in[8];
  const int*   rpi   = (const int*)d_in[9];
  float* out = (float*)d_out;

  char* ws = (char*)d_ws;
  bf16*  xb   = (bf16*)(ws);                      // 77,070,336 B (live for proj residual)
  bf16*  wqb  = (bf16*)(ws + 77070336);           //  3,538,944 B
  bf16*  wpb  = (bf16*)(ws + 80609280);           //  1,179,648 B
  bf16*  comb = (bf16*)(ws + 81788928);           // 12,582,912 B
  bf16*  qkvT = (bf16*)(ws + 94371840);           // 231,211,008 B
  bf16*  aout = (bf16*)(ws + 325582848);          // 77,070,336 B (head-plane [h][M][32])
  bf16*  yb   = (bf16*)(ws + 94371840);           // aliases qkvT (dead after attn)

  prep_kernel<<<46080, 256, 0, stream>>>(x, wqkv, wproj, table, rpi, smask,
                                         xb, wqb, wpb, comb);
  qkv_gemm<<<1764, 512, 131072, stream>>>(xb, wqb, bqkv, qkvT);
  attn_kernel<<<dim3(1024, 6), 256, 0, stream>>>(qkvT, comb, aout);
  proj_gemm<<<2352, 256, 0, stream>>>(aout, wpb, bproj, xb, yb);
  ln_kernel<<<12544, 256, 0, stream>>>(yb, lng, lnb, out);
}